// Round 27
// baseline (271.336 us; speedup 1.0000x reference)
//
#include <hip/hip_runtime.h>
#include <math.h>

#define BATCH   64
#define DIMC    384
#define KEY_DIM 16
#define HEADS   8
#define DD      64
#define DH      512
#define NH_KD   128
#define RES     28
#define RES2    14
#define NN      784
#define NN2     196
#define OUT_DIM 384
#define SCALE   0.25f
#define LOG2E   1.44269504088896340736f
#define XPAD    896     // 7*128
#define QPAD    256     // 2*128
#define KPAD    832     // 13*64
#define XSP     796     // xprep LDS pitch (shorts)

typedef __attribute__((ext_vector_type(8))) short bf16x8;
typedef __attribute__((ext_vector_type(4))) float f32x4;

#define MFMA32(a, b, c) __builtin_amdgcn_mfma_f32_16x16x32_bf16(a, b, c, 0, 0, 0)
#define SWZ(row, bcol) ((row) * 64 + ((bcol) ^ ((((row) >> 1) & 3) << 4)))

__device__ inline short f2bf(float f) {
    unsigned u = __float_as_uint(f);
    unsigned r = (u + 0x7fff + ((u >> 16) & 1)) >> 16;
    return (short)r;
}
__device__ inline float bf2f(short h) {
    return __uint_as_float(((unsigned)(unsigned short)h) << 16);
}
__device__ __forceinline__ unsigned cvt_pk_bf16(float a, float b) {
    unsigned r;
    asm("v_cvt_pk_bf16_f32 %0, %1, %2" : "=v"(r) : "v"(a), "v"(b));
    return r;
}
// raw HW 2^x (args pre-scaled by log2e); v_exp_f32(-inf) = 0 handles pad keys
__device__ __forceinline__ float fexp2(float x) {
    float r;
    asm("v_exp_f32 %0, %1" : "=v"(r) : "v"(x));
    return r;
}
__device__ __forceinline__ void gload16(const void* g, void* l) {
    __builtin_amdgcn_global_load_lds((const __attribute__((address_space(1))) void*)g,
                                     (__attribute__((address_space(3))) void*)l, 16, 0, 0);
}

// ---- ws byte offsets ----
#define O_XT_HI    0u
#define O_QINT_HI  44040192u
#define O_QT       88080384u
#define O_KT       96468992u
#define O_V        123731968u
#define O_VLT      178257920u   // fp32 [b][196][512] transposed vlocal
#define O_BIASB    203948032u
#define O_W_HI     206557184u
#define O_W_LO     207540224u
#define O_ATTNT    0u           // bf16 [b][196][512] (xT dead by attention)
#define O_GT_HI    25690112u    // bf16 [b][256][512]

// ---------------- xprep v2: fused x->xT + dwconv/pool -> qinT, short4-wide stores ----------------
__global__ __launch_bounds__(256)
void xprep_kernel(const float* __restrict__ x, const float* __restrict__ ql_w,
                  const float* __restrict__ ql_b, short* __restrict__ xT,
                  short* __restrict__ qinT) {
    __shared__ short xs[32 * XSP];
    const int cg = blockIdx.x, b = blockIdx.y;
    const int t = threadIdx.x;
    const float* xb = x + ((size_t)b * DIMC + cg * 32) * NN;

    // phase 0: coalesced x load -> bf16 LDS [c][n]
    {
        const int c = t >> 3, sub = t & 7;
        const float* xc = xb + (size_t)c * NN;
        short* dst = xs + c * XSP;
        #pragma unroll 5
        for (int p4 = sub; p4 < 196; p4 += 8) {
            float4 v = *(const float4*)(xc + p4 * 4);
            uint2 pk = {cvt_pk_bf16(v.x, v.y), cvt_pk_bf16(v.z, v.w)};
            *(uint2*)(dst + p4 * 4) = pk;
        }
    }
    __syncthreads();

    const int c4 = (t & 7) * 4;     // 4 channels per thread
    const int ng = t >> 3;          // 0..31

    // phase 1: transposed xT write, short4 per store (8 lanes -> 64B per row)
    {
        short* dstb = xT + (size_t)b * XPAD * DIMC + cg * 32 + c4;
        const short* s0 = xs + (c4 + 0) * XSP;
        const short* s1 = xs + (c4 + 1) * XSP;
        const short* s2 = xs + (c4 + 2) * XSP;
        const short* s3 = xs + (c4 + 3) * XSP;
        for (int n = ng; n < NN; n += 32) {
            short4 v = {s0[n], s1[n], s2[n], s3[n]};
            *(short4*)(dstb + (size_t)n * DIMC) = v;
        }
        const short4 z4 = {0, 0, 0, 0};
        for (int n = NN + ng; n < XPAD; n += 32)
            *(short4*)(dstb + (size_t)n * DIMC) = z4;
    }

    // phase 2: dwconv3x3 s2 (pad1) + pool for 4 channels -> qinT short4 stores
    {
        float wv[4][9], bi[4];
        #pragma unroll
        for (int j = 0; j < 4; ++j) {
            const int c = cg * 32 + c4 + j;
            #pragma unroll
            for (int k = 0; k < 9; ++k) wv[j][k] = ql_w[c * 9 + k];
            bi[j] = ql_b[c];
        }
        short* qdst = qinT + (size_t)b * QPAD * DIMC + cg * 32 + c4;
        for (int n2 = ng; n2 < NN2; n2 += 32) {
            int i = n2 / RES2, jj = n2 % RES2;
            int r0 = 2 * i - 1, cc0 = 2 * jj - 1;
            bool rt = (r0 >= 0), cl = (cc0 >= 0), cr = (cc0 + 2 < RES);
            short4 outv;
            #pragma unroll
            for (int j = 0; j < 4; ++j) {
                const short* xc = xs + (c4 + j) * XSP;
                float acc = bi[j];
                if (rt) {
                    if (cl) acc += bf2f(xc[r0 * RES + cc0])     * wv[j][0];
                            acc += bf2f(xc[r0 * RES + cc0 + 1]) * wv[j][1];
                    if (cr) acc += bf2f(xc[r0 * RES + cc0 + 2]) * wv[j][2];
                }
                {
                    if (cl) acc += bf2f(xc[(r0 + 1) * RES + cc0])     * wv[j][3];
                            acc += bf2f(xc[(r0 + 1) * RES + cc0 + 1]) * wv[j][4];
                    if (cr) acc += bf2f(xc[(r0 + 1) * RES + cc0 + 2]) * wv[j][5];
                }
                {
                    if (cl) acc += bf2f(xc[(r0 + 2) * RES + cc0])     * wv[j][6];
                            acc += bf2f(xc[(r0 + 2) * RES + cc0 + 1]) * wv[j][7];
                    if (cr) acc += bf2f(xc[(r0 + 2) * RES + cc0 + 2]) * wv[j][8];
                }
                acc += bf2f(xc[(2 * i) * RES + 2 * jj]);   // pool
                ((short*)&outv)[j] = f2bf(acc);
            }
            *(short4*)(qdst + (size_t)n2 * DIMC) = outv;
        }
        const short4 z4 = {0, 0, 0, 0};
        for (int n2 = NN2 + ng; n2 < QPAD; n2 += 32)
            *(short4*)(qdst + (size_t)n2 * DIMC) = z4;
    }
}

// ---------------- weight split ----------------
__global__ void wsplit_kernel(const float* __restrict__ w0, const float* __restrict__ w1,
                              const float* __restrict__ w2, const float* __restrict__ w3,
                              short* __restrict__ hi, short* __restrict__ lo) {
    int i = blockIdx.x * 256 + threadIdx.x;
    if (i >= 491520) return;
    const float* src; int j = i;
    if (j < 49152) src = w0;
    else if (j < 98304) { src = w1; j -= 49152; }
    else if (j < 294912) { src = w2; j -= 98304; }
    else { src = w3; j -= 294912; }
    float v = src[j];
    short h = f2bf(v);
    hi[i] = h;
    lo[i] = f2bf(v - bf2f(h));
}

// ---------------- bf16 MFMA GEMM (unchanged) ----------------
template<bool WLO, bool SWAP>
__global__ __launch_bounds__(256)
void gemm_split_kernel(const short* __restrict__ wgt_hi, const short* __restrict__ wgt_lo,
                       const short* __restrict__ act,
                       const float* __restrict__ bias, const float* __restrict__ s,
                       const float* __restrict__ off,
                       float* __restrict__ out_f, short* __restrict__ out_b,
                       int mode, int C, int Nn, int Npad, int NPADo, float pscale,
                       int NXn, int NYo, int O) {
    constexpr int NT = 2 + (WLO ? 1 : 0);
    constexpr int STRIDE = NT * 8192;
    constexpr int OFF_A = 0, OFF_B = 8192, OFF_WL = 16384;
    __shared__ __align__(1024) char LDS[2 * STRIDE];

    const int bid = blockIdx.x;
    const int xcd = bid & 7;
    const int g   = bid >> 3;
    const int ot  = g % NYo;
    const int pp  = (g / NYo) * 8 + xcd;
    const int nt  = pp % NXn;
    const int b   = pp / NXn;
    const int n0 = nt * 128, o0 = ot * 128;

    const int t = threadIdx.x;
    const int lane = t & 63, wid = t >> 6;
    const int wm = wid & 1, wn = wid >> 1;
    const int lr = lane & 15, kg = lane >> 4;

    const short* Ahi = SWAP ? act : wgt_hi;
    const short* Bhi = SWAP ? wgt_hi : act;

    f32x4 acc[4][4];
    #pragma unroll
    for (int m = 0; m < 4; ++m)
        #pragma unroll
        for (int n = 0; n < 4; ++n)
            acc[m][n] = (f32x4){0.f, 0.f, 0.f, 0.f};

    const int ccol = (lane & 3) * 16;
    const int r0   = wid * 32 + (lane >> 2);

    auto STAGE = [&](int buf, int k0) {
        char* base = LDS + buf * STRIDE;
        #pragma unroll
        for (int c = 0; c < 2; ++c) {
            int r = r0 + c * 16;
            int bcs = ccol ^ (((r >> 1) & 3) << 4);
            size_t aRow = SWAP ? ((size_t)b * Npad + n0 + r) : (size_t)(o0 + r);
            size_t bRow = SWAP ? (size_t)(o0 + r) : ((size_t)b * Npad + n0 + r);
            char* ldsc = base + wid * 2048 + c * 1024;
            gload16((const char*)Ahi + (aRow * C + k0) * 2 + bcs, ldsc + OFF_A);
            gload16((const char*)Bhi + (bRow * C + k0) * 2 + bcs, ldsc + OFF_B);
            if constexpr (WLO)
                gload16((const char*)wgt_lo + ((size_t)(o0 + r) * C + k0) * 2 + bcs, ldsc + OFF_WL);
        }
    };

    STAGE(0, 0);
    int cur = 0;
    __syncthreads();

    for (int k0 = 0;; k0 += 32) {
        const bool hasNext = (k0 + 32 < C);
        if (hasNext) STAGE(cur ^ 1, k0 + 32);

        char* cb = LDS + cur * STRIDE;
        bf16x8 ah[4], wlm[4];
        #pragma unroll
        for (int m = 0; m < 4; ++m) {
            int row = wm * 64 + m * 16 + lr;
            ah[m] = *(const bf16x8*)(cb + OFF_A + SWZ(row, kg * 16));
            if constexpr (WLO) if (!SWAP) wlm[m] = *(const bf16x8*)(cb + OFF_WL + SWZ(row, kg * 16));
        }
        #pragma unroll
        for (int nf = 0; nf < 4; ++nf) {
            int row = wn * 64 + nf * 16 + lr;
            bf16x8 bh = *(const bf16x8*)(cb + OFF_B + SWZ(row, kg * 16));
            bf16x8 blw;
            if constexpr (WLO) if (SWAP) blw = *(const bf16x8*)(cb + OFF_WL + SWZ(row, kg * 16));
            #pragma unroll
            for (int m = 0; m < 4; ++m) {
                acc[m][nf] = MFMA32(ah[m], bh, acc[m][nf]);
                if constexpr (WLO) {
                    if (SWAP) acc[m][nf] = MFMA32(ah[m], blw, acc[m][nf]);
                    else      acc[m][nf] = MFMA32(wlm[m], bh, acc[m][nf]);
                }
            }
        }
        if (!hasNext) break;
        __syncthreads();
        cur ^= 1;
    }

    if (mode == 2) {
        #pragma unroll
        for (int m = 0; m < 4; ++m) {
            #pragma unroll
            for (int nf = 0; nf < 4; ++nf) {
                int col = n0 + wn * 64 + nf * 16 + lr;
                if (col >= NPADo) continue;
                int hh = (o0 + wm * 64 + m * 16) >> 4;
                bool nok = (col < Nn);
                float v[4];
                #pragma unroll
                for (int r = 0; r < 4; ++r) {
                    int row = o0 + wm * 64 + m * 16 + kg * 4 + r;
                    float a = s[row];
                    v[r] = nok ? (acc[m][nf][r] * a + (bias[row] * a + off[row])) * pscale : 0.f;
                }
                unsigned h01 = cvt_pk_bf16(v[0], v[1]);
                unsigned h23 = cvt_pk_bf16(v[2], v[3]);
                float l0 = v[0] - __uint_as_float(h01 << 16);
                float l1 = v[1] - __uint_as_float(h01 & 0xffff0000u);
                float l2 = v[2] - __uint_as_float(h23 << 16);
                float l3 = v[3] - __uint_as_float(h23 & 0xffff0000u);
                uint2 hst = {h01, h23};
                uint2 lst = {cvt_pk_bf16(l0, l1), cvt_pk_bf16(l2, l3)};
                size_t base = ((size_t)(b * 8 + hh) * NPADo + col) * 32 + kg * 4;
                *(uint2*)(out_b + base)      = hst;
                *(uint2*)(out_b + base + 16) = lst;
            }
        }
    } else {
        #pragma unroll
        for (int nf = 0; nf < 4; ++nf) {
            int col_d = o0 + wn * 64 + nf * 16 + lr;
            float a = s[col_d];
            float badd = bias[col_d] * a + off[col_d];
            #pragma unroll
            for (int m = 0; m < 4; ++m) {
                int rown = n0 + wm * 64 + m * 16 + kg * 4;
                float v0 = acc[m][nf][0] * a + badd;
                float v1 = acc[m][nf][1] * a + badd;
                float v2 = acc[m][nf][2] * a + badd;
                float v3 = acc[m][nf][3] * a + badd;
                if (mode == 0) {
                    if (rown < Nn) {
                        float4 vv = {v0, v1, v2, v3};
                        *(float4*)(out_f + ((size_t)b * O + col_d) * Nn + rown) = vv;
                    }
                } else {
                    if (rown + 3 < NPADo) {
                        uint2 st = {cvt_pk_bf16(v0, v1), cvt_pk_bf16(v2, v3)};
                        *(uint2*)(out_b + ((size_t)b * O + col_d) * NPADo + rown) = st;
                    }
                }
            }
        }
    }
}

// ---------------- vlocalT: bn(dwconv) -> TRANSPOSED fp32 [b][196][512] ----------------
__global__ __launch_bounds__(256)
void vlocalT_kernel(const short* __restrict__ v,
                    const float* __restrict__ vl_w, const float* __restrict__ vl_b,
                    const float* __restrict__ vl_s, const float* __restrict__ vl_o,
                    float* __restrict__ vlT) {
    __shared__ float tile[32][201];
    const int cg = blockIdx.x, b = blockIdx.y;
    const int t = threadIdx.x;
    {
        const int c_l = t >> 3, nsub = t & 7;
        const int c = cg * 32 + c_l;
        const size_t base = ((size_t)b * DH + c) * KPAD;
        const float* w = vl_w + c * 9;
        const float w0 = w[0], w1 = w[1], w2 = w[2], w3 = w[3], w4 = w[4],
                    w5 = w[5], w6 = w[6], w7 = w[7], w8 = w[8];
        const float bias = vl_b[c], sc = vl_s[c], of = vl_o[c];
        for (int n2 = nsub; n2 < NN2; n2 += 8) {
            int i = n2 / RES2, j = n2 % RES2;
            int r0 = 2 * i - 1, c0 = 2 * j - 1;
            float acc = bias;
            if (r0 >= 0) {
                if (c0 >= 0)       acc += bf2f(v[base + r0 * RES + c0])     * w0;
                                   acc += bf2f(v[base + r0 * RES + c0 + 1]) * w1;
                if (c0 + 2 < RES)  acc += bf2f(v[base + r0 * RES + c0 + 2]) * w2;
            }
            {
                if (c0 >= 0)       acc += bf2f(v[base + (r0 + 1) * RES + c0])     * w3;
                                   acc += bf2f(v[base + (r0 + 1) * RES + c0 + 1]) * w4;
                if (c0 + 2 < RES)  acc += bf2f(v[base + (r0 + 1) * RES + c0 + 2]) * w5;
            }
            if (r0 + 2 < RES) {
                if (c0 >= 0)       acc += bf2f(v[base + (r0 + 2) * RES + c0])     * w6;
                                   acc += bf2f(v[base + (r0 + 2) * RES + c0 + 1]) * w7;
                if (c0 + 2 < RES)  acc += bf2f(v[base + (r0 + 2) * RES + c0 + 2]) * w8;
            }
            tile[c_l][n2] = acc * sc + of;
        }
    }
    __syncthreads();
    {
        const int c_l = t & 31, ng = t >> 5;
        for (int n2 = ng; n2 < NN2; n2 += 8)
            vlT[((size_t)b * NN2 + n2) * DH + cg * 32 + c_l] = tile[c_l][n2];
    }
}

// ---------------- bias expand: * log2e; pad keys = -inf (exp -> 0) ----------------
__global__ void biasB_expand_kernel(const float* __restrict__ ab, const int* __restrict__ bidx,
                                    short* __restrict__ biasB, int n_off) {
    int i = blockIdx.x * 256 + threadIdx.x;
    int h = blockIdx.y;
    if (i >= NN2 * KPAD) return;
    int q = i / KPAD, key = i - q * KPAD;
    short v = (short)0xFF80;    // bf16 -inf
    if (key < NN) v = f2bf(ab[h * n_off + bidx[q * NN + key]] * LOG2E);
    biasB[(size_t)h * NN2 * KPAD + i] = v;
}

// ---------------- MFMA attention v15: counted-vmcnt prefetch-depth-2 (T4) ----------------
// 3 staging buffers (t, t+1, t+2) + raw s_barrier with counted vmcnt: prefetched
// loads stay in flight across barriers (no full vmcnt(0) drain per tile).
// Waves 0-3 issue 2 gload_lds per STAGE, waves 4-7 issue 1 -> wave-uniform literals.
__global__ __launch_bounds__(512, 4)
void attn_mfma15_kernel(const short* __restrict__ QT, const short* __restrict__ KT,
                        const short* __restrict__ V, const short* __restrict__ biasB,
                        short* __restrict__ outT) {
    // [3 bufs][K 4KB | V 8KB] + Ps[8 waves][2KB] = 53248 B (grid-limited 2 blocks/CU)
    __shared__ __align__(1024) char LDS[3 * 12288 + 8 * 2048];

    const int t = threadIdx.x;
    const int bid = blockIdx.x;
    const int h = bid & 7;
    const int b = bid >> 3;

    const int lane = t & 63, wid = t >> 6;
    const int lr = lane & 15, kg = lane >> 4;
    const int wq0 = wid * 32;

    bf16x8 qb1[2], qb2[2];
    const short* bb[2];
    #pragma unroll
    for (int qf = 0; qf < 2; ++qf) {
        int qg = wq0 + qf * 16 + lr;
        const short* qrow = QT + ((size_t)(b * 8 + h) * QPAD + qg) * 32;
        qb1[qf] = *(const bf16x8*)(qrow + (kg & 1) * 8);
        qb2[qf] = (bf16x8){0, 0, 0, 0, 0, 0, 0, 0};
        if (kg < 2) qb2[qf] = *(const bf16x8*)(qrow + 16 + kg * 8);
        int qs = (qg < NN2) ? qg : (NN2 - 1);
        bb[qf] = biasB + ((size_t)h * NN2 + qs) * KPAD;
    }

    const short* kbase = KT + (size_t)(b * 8 + h) * KPAD * 32;
    const short* vbase = V + ((size_t)b * DH + h * DD) * KPAD;

    f32x4 acc[2][4];
    #pragma unroll
    for (int qf = 0; qf < 2; ++qf)
        #pragma unroll
        for (int nt = 0; nt < 4; ++nt)
            acc[qf][nt] = (f32x4){0.f, 0.f, 0.f, 0.f};
    float sacc[2] = {0.f, 0.f};
    char* PsW = LDS + 36864 + wid * 2048;
    const int swz = (lr & 7) << 4;

    auto STAGE = [&](int buf, int tile) {
        const int k0 = tile * 64;
        char* base = LDS + buf * 12288;
        #pragma unroll
        for (int ci = 0; ci < 2; ++ci) {
            if (ci == 1 && wid >= 4) continue;
            int chunk = (ci == 0) ? wid : wid + 8;
            if (chunk < 4) {
                int row = chunk * 16 + (lane >> 2);
                int pcol = (lane & 3) ^ ((row >> 1) & 3);
                gload16((const char*)(kbase + (size_t)(k0 + row) * 32) + pcol * 16,
                        base + chunk * 1024);
            } else {
                int vrow = (chunk - 4) * 8 + (lane >> 3);
                int pcol = (lane & 7) ^ (vrow & 7);
                gload16((const char*)(vbase + (size_t)vrow * KPAD + k0) + pcol * 16,
                        base + 4096 + (chunk - 4) * 1024);
            }
        }
    };

    auto COMPUTE = [&](int buf, int tile) {
        const int k0 = tile * 64;
        char* cb = LDS + buf * 12288;

        #pragma unroll
        for (int qf = 0; qf < 2; ++qf) {
            short4 b4[4];
            #pragma unroll
            for (int nt = 0; nt < 4; ++nt)
                b4[nt] = *(const short4*)(bb[qf] + k0 + nt * 16 + kg * 4);

            f32x4 sc[4];
            __builtin_amdgcn_s_setprio(1);
            #pragma unroll
            for (int nt = 0; nt < 4; ++nt) {
                int row = nt * 16 + lr;
                bf16x8 ka = *(const bf16x8*)(cb + row * 64 + ((kg ^ ((row >> 1) & 3)) * 16));
                sc[nt] = (f32x4){0.f, 0.f, 0.f, 0.f};
                sc[nt] = MFMA32(ka, qb1[qf], sc[nt]);
                sc[nt] = MFMA32(ka, qb2[qf], sc[nt]);
            }
            __builtin_amdgcn_s_setprio(0);

            #pragma unroll
            for (int nt = 0; nt < 4; ++nt) {
                float pv[4];
                #pragma unroll
                for (int r = 0; r < 4; ++r) {
                    float sv = sc[nt][r] + bf2f(((const short*)&b4[nt])[r]);
                    pv[r] = fexp2(sv);
                    sacc[qf] += pv[r];
                }
                uint2 pk2 = {cvt_pk_bf16(pv[0], pv[1]), cvt_pk_bf16(pv[2], pv[3])};
                *(uint2*)(PsW + lr * 128 + ((nt * 32 + kg * 8) ^ swz)) = pk2;
            }

            #pragma unroll
            for (int ks = 0; ks < 2; ++ks) {
                bf16x8 pa = *(const bf16x8*)(PsW + lr * 128 + ((ks * 64 + kg * 16) ^ swz));
                __builtin_amdgcn_s_setprio(1);
                #pragma unroll
                for (int nt = 0; nt < 4; ++nt) {
                    int row = nt * 16 + lr;
                    int pk_ = ks * 4 + kg;
                    bf16x8 vf = *(const bf16x8*)(cb + 4096 + row * 128 + ((pk_ ^ (row & 7)) * 16));
                    acc[qf][nt] = MFMA32(pa, vf, acc[qf][nt]);
                }
                __builtin_amdgcn_s_setprio(0);
            }
        }
    };

    // prologue: issue tiles 0 and 1; wait only for tile 0 (tile 1 stays in flight)
    STAGE(0, 0);
    STAGE(1, 1);
    if (wid < 4) asm volatile("s_waitcnt vmcnt(2)" ::: "memory");
    else         asm volatile("s_waitcnt vmcnt(1)" ::: "memory");
    __builtin_amdgcn_s_barrier();
    __builtin_amdgcn_sched_barrier(0);

    #pragma unroll 1
    for (int tile = 0; tile < 13; ++tile) {
        COMPUTE(tile % 3, tile);
        if (tile == 12) break;
        if (tile + 2 < 13) {
            STAGE((tile + 2) % 3, tile + 2);
            // wait tile+1's loads landed; tile+2's (2 or 1 per wave) stay in flight
            if (wid < 4) asm volatile("s_waitcnt vmcnt(2)" ::: "memory");
            else         asm volatile("s_waitcnt vmcnt(1)" ::: "memory");
        } else {
            asm volatile("s_waitcnt vmcnt(0)" ::: "memory");
        }
        __builtin_amdgcn_s_barrier();
        __builtin_amdgcn_sched_barrier(0);
    }

    #pragma unroll
    for (int qf = 0; qf < 2; ++qf) {
        float sv = sacc[qf];
        sv += __shfl_xor(sv, 16, 64);
        sv += __shfl_xor(sv, 32, 64);
        #pragma unroll
        for (int r = 0; r < 4; ++r) {
            int qrow_ = wq0 + qf * 16 + kg * 4 + r;
            if (qrow_ >= NN2) continue;
            float inv = 1.f / __shfl(sv, kg * 4 + r, 64);
            short* grow = outT + ((size_t)b * NN2 + qrow_) * DH + h * DD;
            #pragma unroll
            for (int nt = 0; nt < 4; ++nt) {
                int d = nt * 16 + lr;
                grow[d] = f2bf(acc[qf][nt][r] * inv);
            }
        }
    }
}

// ---------------- geluE: elementwise gelu(bf16 attnT + fp32 vlT) -> gT bf16 ----------------
__global__ __launch_bounds__(256)
void geluE_kernel(const short* __restrict__ aT, const float* __restrict__ vlT,
                  short* __restrict__ gT) {
    int i = blockIdx.x * 256 + threadIdx.x;
    int d0 = (i & 63) * 8;
    int n2 = (i >> 6) & (QPAD - 1);
    int b  = i >> 14;
    short* gp = gT + ((size_t)b * QPAD + n2) * DH + d0;
    if (n2 >= NN2) {
        *(uint4*)gp = (uint4){0u, 0u, 0u, 0u};
        return;
    }
    size_t ao = ((size_t)b * NN2 + n2) * DH + d0;
    bf16x8 av = *(const bf16x8*)(aT + ao);
    float4 v0 = *(const float4*)(vlT + ao);
    float4 v1 = *(const float4*)(vlT + ao + 4);
    float s[8];
    #pragma unroll
    for (int k = 0; k < 4; ++k) s[k] = bf2f(av[k]) + ((const float*)&v0)[k];
    #pragma unroll
    for (int k = 0; k < 4; ++k) s[4 + k] = bf2f(av[4 + k]) + ((const float*)&v1)[k];
    float g[8];
    #pragma unroll
    for (int k = 0; k < 8; ++k)
        g[k] = 0.5f * s[k] * (1.f + erff(s[k] * 0.70710678118654752440f));
    uint4 st = {cvt_pk_bf16(g[0], g[1]), cvt_pk_bf16(g[2], g[3]),
                cvt_pk_bf16(g[4], g[5]), cvt_pk_bf16(g[6], g[7])};
    *(uint4*)gp = st;
}

extern "C" void kernel_launch(void* const* d_in, const int* in_sizes, int n_in,
                              void* d_out, int out_size, void* d_ws, size_t ws_size,
                              hipStream_t stream) {
    const float* x     = (const float*)d_in[0];
    const float* ql_w  = (const float*)d_in[1];
    const float* ql_b  = (const float*)d_in[2];
    const float* qp_w  = (const float*)d_in[3];
    const float* qp_b  = (const float*)d_in[4];
    const float* qp_s  = (const float*)d_in[5];
    const float* qp_o  = (const float*)d_in[6];
    const float* k_w   = (const float*)d_in[7];
    const float* k_b   = (const float*)d_in[8];
    const float* k_s   = (const float*)d_in[9];
    const float* k_o   = (const float*)d_in[10];
    const float* v_w   = (const float*)d_in[11];
    const float* v_b   = (const float*)d_in[12];
    const float* v_s   = (const float*)d_in[13];
    const float* v_o   = (const float*)d_in[14];
    const float* vl_w  = (const float*)d_in[15];
    const float* vl_b  = (const float*)d_in[16];
    const float* vl_s  = (const float*)d_in[17];
    const float* vl_o  = (const float*)d_in[18];
    const float* p_w   = (const float*)d_in[19];
    const float* p_b   = (const float*)d_in[20];
    const float* p_s   = (const float*)d_in[21];
    const float* p_o   = (const float*)d_in[22];
    const float* ab    = (const float*)d_in[23];
    const int*   bidx  = (const int*)d_in[24];
    float* out = (float*)d_out;
    int n_off = in_sizes[23] / HEADS;

    char* ws = (char*)d_ws;
    short* qinT_h = (short*)(ws + O_QINT_HI);
    short* xT_h   = (short*)(ws + O_XT_HI);
    short* QT     = (short*)(ws + O_QT);
    short* KT     = (short*)(ws + O_KT);
    short* Vb     = (short*)(ws + O_V);
    float* vlT    = (float*)(ws + O_VLT);
    short* biasB  = (short*)(ws + O_BIASB);
    short* w_h    = (short*)(ws + O_W_HI);
    short* w_l    = (short*)(ws + O_W_LO);
    short* attnT  = (short*)(ws + O_ATTNT);
    short* gT_h   = (short*)(ws + O_GT_HI);

    // 1. xprep
    xprep_kernel<<<dim3(DIMC / 32, BATCH), 256, 0, stream>>>(x, ql_w, ql_b, xT_h, qinT_h);
    // 2. weight splits
    wsplit_kernel<<<dim3(1920), 256, 0, stream>>>(qp_w, k_w, v_w, p_w, w_h, w_l);
    // 3. q projection -> QT packed (pre-scaled by SCALE*log2e)
    gemm_split_kernel<false, false><<<dim3(128), 256, 0, stream>>>(
        w_h + 0, nullptr, qinT_h, qp_b, qp_s, qp_o,
        nullptr, QT, 2, DIMC, NN2, QPAD, QPAD, SCALE * LOG2E, 2, 1, 128);
    // 4. k projection -> KT packed
    gemm_split_kernel<false, false><<<dim3(448), 256, 0, stream>>>(
        w_h + 49152, nullptr, xT_h, k_b, k_s, k_o,
        nullptr, KT, 2, DIMC, NN, XPAD, KPAD, 1.0f, 7, 1, 128);
    // 5. v projection -> bf16, SWAPPED
    gemm_split_kernel<false, true><<<dim3(1792), 256, 0, stream>>>(
        w_h + 98304, nullptr, xT_h, v_b, v_s, v_o,
        nullptr, Vb, 1, DIMC, NN, XPAD, KPAD, 1.0f, 7, 4, 512);
    // 6. vlocalT (transposed fp32)
    vlocalT_kernel<<<dim3(DH / 32, BATCH), 256, 0, stream>>>(Vb, vl_w, vl_b, vl_s, vl_o, vlT);
    // 7. bias expand (log2e; pad keys -inf)
    biasB_expand_kernel<<<dim3((NN2 * KPAD + 255) / 256, HEADS), 256, 0, stream>>>(ab, bidx, biasB, n_off);
    // 8. attention -> attnT bf16 (counted-vmcnt pipeline)
    attn_mfma15_kernel<<<dim3(HEADS * BATCH), 512, 0, stream>>>(QT, KT, Vb, biasB, attnT);
    // 9. elementwise gelu -> gT bf16 (zero-fills pad rows)
    geluE_kernel<<<dim3(4096), 256, 0, stream>>>(attnT, vlT, gT_h);
    // 10. output projection, SWAPPED, single-term weights
    gemm_split_kernel<false, true><<<dim3(384), 256, 0, stream>>>(
        w_h + 294912, nullptr, gT_h, p_b, p_s, p_o,
        out, nullptr, 0, DH, NN2, QPAD, 0, 1.0f, 2, 3, 384);
}

// Round 28
// 260.293 us; speedup vs baseline: 1.0424x; 1.0424x over previous
//
#include <hip/hip_runtime.h>
#include <math.h>

#define BATCH   64
#define DIMC    384
#define KEY_DIM 16
#define HEADS   8
#define DD      64
#define DH      512
#define NH_KD   128
#define RES     28
#define RES2    14
#define NN      784
#define NN2     196
#define OUT_DIM 384
#define SCALE   0.25f
#define LOG2E   1.44269504088896340736f
#define XPAD    896     // 7*128
#define QPAD    256     // 2*128
#define KPAD    832     // 13*64
#define XSP     796     // xprep LDS pitch (shorts)

typedef __attribute__((ext_vector_type(8))) short bf16x8;
typedef __attribute__((ext_vector_type(4))) float f32x4;

#define MFMA32(a, b, c) __builtin_amdgcn_mfma_f32_16x16x32_bf16(a, b, c, 0, 0, 0)
#define SWZ(row, bcol) ((row) * 64 + ((bcol) ^ ((((row) >> 1) & 3) << 4)))

__device__ inline short f2bf(float f) {
    unsigned u = __float_as_uint(f);
    unsigned r = (u + 0x7fff + ((u >> 16) & 1)) >> 16;
    return (short)r;
}
__device__ inline float bf2f(short h) {
    return __uint_as_float(((unsigned)(unsigned short)h) << 16);
}
__device__ __forceinline__ unsigned cvt_pk_bf16(float a, float b) {
    unsigned r;
    asm("v_cvt_pk_bf16_f32 %0, %1, %2" : "=v"(r) : "v"(a), "v"(b));
    return r;
}
// raw HW 2^x (args pre-scaled by log2e); v_exp_f32(-inf) = 0 handles pad keys
__device__ __forceinline__ float fexp2(float x) {
    float r;
    asm("v_exp_f32 %0, %1" : "=v"(r) : "v"(x));
    return r;
}
__device__ __forceinline__ void gload16(const void* g, void* l) {
    __builtin_amdgcn_global_load_lds((const __attribute__((address_space(1))) void*)g,
                                     (__attribute__((address_space(3))) void*)l, 16, 0, 0);
}

// ---- ws byte offsets ----
#define O_XT_HI    0u
#define O_QINT_HI  44040192u
#define O_QT       88080384u
#define O_KT       96468992u
#define O_V        123731968u
#define O_VLT      178257920u   // fp32 [b][196][512] transposed vlocal
#define O_BIASB    203948032u
#define O_W_HI     206557184u
#define O_W_LO     207540224u
#define O_ATTNT    0u           // bf16 [b][196][512] (xT dead by attention)
#define O_GT_HI    25690112u    // bf16 [b][256][512]

// ---------------- xprep v2: fused x->xT + dwconv/pool -> qinT, short4-wide stores ----------------
__global__ __launch_bounds__(256)
void xprep_kernel(const float* __restrict__ x, const float* __restrict__ ql_w,
                  const float* __restrict__ ql_b, short* __restrict__ xT,
                  short* __restrict__ qinT) {
    __shared__ short xs[32 * XSP];
    const int cg = blockIdx.x, b = blockIdx.y;
    const int t = threadIdx.x;
    const float* xb = x + ((size_t)b * DIMC + cg * 32) * NN;

    // phase 0: coalesced x load -> bf16 LDS [c][n]
    {
        const int c = t >> 3, sub = t & 7;
        const float* xc = xb + (size_t)c * NN;
        short* dst = xs + c * XSP;
        #pragma unroll 5
        for (int p4 = sub; p4 < 196; p4 += 8) {
            float4 v = *(const float4*)(xc + p4 * 4);
            uint2 pk = {cvt_pk_bf16(v.x, v.y), cvt_pk_bf16(v.z, v.w)};
            *(uint2*)(dst + p4 * 4) = pk;
        }
    }
    __syncthreads();

    const int c4 = (t & 7) * 4;     // 4 channels per thread
    const int ng = t >> 3;          // 0..31

    // phase 1: transposed xT write, short4 per store (8 lanes -> 64B per row)
    {
        short* dstb = xT + (size_t)b * XPAD * DIMC + cg * 32 + c4;
        const short* s0 = xs + (c4 + 0) * XSP;
        const short* s1 = xs + (c4 + 1) * XSP;
        const short* s2 = xs + (c4 + 2) * XSP;
        const short* s3 = xs + (c4 + 3) * XSP;
        for (int n = ng; n < NN; n += 32) {
            short4 v = {s0[n], s1[n], s2[n], s3[n]};
            *(short4*)(dstb + (size_t)n * DIMC) = v;
        }
        const short4 z4 = {0, 0, 0, 0};
        for (int n = NN + ng; n < XPAD; n += 32)
            *(short4*)(dstb + (size_t)n * DIMC) = z4;
    }

    // phase 2: dwconv3x3 s2 (pad1) + pool for 4 channels -> qinT short4 stores
    {
        float wv[4][9], bi[4];
        #pragma unroll
        for (int j = 0; j < 4; ++j) {
            const int c = cg * 32 + c4 + j;
            #pragma unroll
            for (int k = 0; k < 9; ++k) wv[j][k] = ql_w[c * 9 + k];
            bi[j] = ql_b[c];
        }
        short* qdst = qinT + (size_t)b * QPAD * DIMC + cg * 32 + c4;
        for (int n2 = ng; n2 < NN2; n2 += 32) {
            int i = n2 / RES2, jj = n2 % RES2;
            int r0 = 2 * i - 1, cc0 = 2 * jj - 1;
            bool rt = (r0 >= 0), cl = (cc0 >= 0), cr = (cc0 + 2 < RES);
            short4 outv;
            #pragma unroll
            for (int j = 0; j < 4; ++j) {
                const short* xc = xs + (c4 + j) * XSP;
                float acc = bi[j];
                if (rt) {
                    if (cl) acc += bf2f(xc[r0 * RES + cc0])     * wv[j][0];
                            acc += bf2f(xc[r0 * RES + cc0 + 1]) * wv[j][1];
                    if (cr) acc += bf2f(xc[r0 * RES + cc0 + 2]) * wv[j][2];
                }
                {
                    if (cl) acc += bf2f(xc[(r0 + 1) * RES + cc0])     * wv[j][3];
                            acc += bf2f(xc[(r0 + 1) * RES + cc0 + 1]) * wv[j][4];
                    if (cr) acc += bf2f(xc[(r0 + 1) * RES + cc0 + 2]) * wv[j][5];
                }
                {
                    if (cl) acc += bf2f(xc[(r0 + 2) * RES + cc0])     * wv[j][6];
                            acc += bf2f(xc[(r0 + 2) * RES + cc0 + 1]) * wv[j][7];
                    if (cr) acc += bf2f(xc[(r0 + 2) * RES + cc0 + 2]) * wv[j][8];
                }
                acc += bf2f(xc[(2 * i) * RES + 2 * jj]);   // pool
                ((short*)&outv)[j] = f2bf(acc);
            }
            *(short4*)(qdst + (size_t)n2 * DIMC) = outv;
        }
        const short4 z4 = {0, 0, 0, 0};
        for (int n2 = NN2 + ng; n2 < QPAD; n2 += 32)
            *(short4*)(qdst + (size_t)n2 * DIMC) = z4;
    }
}

// ---------------- weight split ----------------
__global__ void wsplit_kernel(const float* __restrict__ w0, const float* __restrict__ w1,
                              const float* __restrict__ w2, const float* __restrict__ w3,
                              short* __restrict__ hi, short* __restrict__ lo) {
    int i = blockIdx.x * 256 + threadIdx.x;
    if (i >= 491520) return;
    const float* src; int j = i;
    if (j < 49152) src = w0;
    else if (j < 98304) { src = w1; j -= 49152; }
    else if (j < 294912) { src = w2; j -= 98304; }
    else { src = w3; j -= 294912; }
    float v = src[j];
    short h = f2bf(v);
    hi[i] = h;
    lo[i] = f2bf(v - bf2f(h));
}

// ---------------- bf16 MFMA GEMM (unchanged) ----------------
template<bool WLO, bool SWAP>
__global__ __launch_bounds__(256)
void gemm_split_kernel(const short* __restrict__ wgt_hi, const short* __restrict__ wgt_lo,
                       const short* __restrict__ act,
                       const float* __restrict__ bias, const float* __restrict__ s,
                       const float* __restrict__ off,
                       float* __restrict__ out_f, short* __restrict__ out_b,
                       int mode, int C, int Nn, int Npad, int NPADo, float pscale,
                       int NXn, int NYo, int O) {
    constexpr int NT = 2 + (WLO ? 1 : 0);
    constexpr int STRIDE = NT * 8192;
    constexpr int OFF_A = 0, OFF_B = 8192, OFF_WL = 16384;
    __shared__ __align__(1024) char LDS[2 * STRIDE];

    const int bid = blockIdx.x;
    const int xcd = bid & 7;
    const int g   = bid >> 3;
    const int ot  = g % NYo;
    const int pp  = (g / NYo) * 8 + xcd;
    const int nt  = pp % NXn;
    const int b   = pp / NXn;
    const int n0 = nt * 128, o0 = ot * 128;

    const int t = threadIdx.x;
    const int lane = t & 63, wid = t >> 6;
    const int wm = wid & 1, wn = wid >> 1;
    const int lr = lane & 15, kg = lane >> 4;

    const short* Ahi = SWAP ? act : wgt_hi;
    const short* Bhi = SWAP ? wgt_hi : act;

    f32x4 acc[4][4];
    #pragma unroll
    for (int m = 0; m < 4; ++m)
        #pragma unroll
        for (int n = 0; n < 4; ++n)
            acc[m][n] = (f32x4){0.f, 0.f, 0.f, 0.f};

    const int ccol = (lane & 3) * 16;
    const int r0   = wid * 32 + (lane >> 2);

    auto STAGE = [&](int buf, int k0) {
        char* base = LDS + buf * STRIDE;
        #pragma unroll
        for (int c = 0; c < 2; ++c) {
            int r = r0 + c * 16;
            int bcs = ccol ^ (((r >> 1) & 3) << 4);
            size_t aRow = SWAP ? ((size_t)b * Npad + n0 + r) : (size_t)(o0 + r);
            size_t bRow = SWAP ? (size_t)(o0 + r) : ((size_t)b * Npad + n0 + r);
            char* ldsc = base + wid * 2048 + c * 1024;
            gload16((const char*)Ahi + (aRow * C + k0) * 2 + bcs, ldsc + OFF_A);
            gload16((const char*)Bhi + (bRow * C + k0) * 2 + bcs, ldsc + OFF_B);
            if constexpr (WLO)
                gload16((const char*)wgt_lo + ((size_t)(o0 + r) * C + k0) * 2 + bcs, ldsc + OFF_WL);
        }
    };

    STAGE(0, 0);
    int cur = 0;
    __syncthreads();

    for (int k0 = 0;; k0 += 32) {
        const bool hasNext = (k0 + 32 < C);
        if (hasNext) STAGE(cur ^ 1, k0 + 32);

        char* cb = LDS + cur * STRIDE;
        bf16x8 ah[4], wlm[4];
        #pragma unroll
        for (int m = 0; m < 4; ++m) {
            int row = wm * 64 + m * 16 + lr;
            ah[m] = *(const bf16x8*)(cb + OFF_A + SWZ(row, kg * 16));
            if constexpr (WLO) if (!SWAP) wlm[m] = *(const bf16x8*)(cb + OFF_WL + SWZ(row, kg * 16));
        }
        #pragma unroll
        for (int nf = 0; nf < 4; ++nf) {
            int row = wn * 64 + nf * 16 + lr;
            bf16x8 bh = *(const bf16x8*)(cb + OFF_B + SWZ(row, kg * 16));
            bf16x8 blw;
            if constexpr (WLO) if (SWAP) blw = *(const bf16x8*)(cb + OFF_WL + SWZ(row, kg * 16));
            #pragma unroll
            for (int m = 0; m < 4; ++m) {
                acc[m][nf] = MFMA32(ah[m], bh, acc[m][nf]);
                if constexpr (WLO) {
                    if (SWAP) acc[m][nf] = MFMA32(ah[m], blw, acc[m][nf]);
                    else      acc[m][nf] = MFMA32(wlm[m], bh, acc[m][nf]);
                }
            }
        }
        if (!hasNext) break;
        __syncthreads();
        cur ^= 1;
    }

    if (mode == 2) {
        #pragma unroll
        for (int m = 0; m < 4; ++m) {
            #pragma unroll
            for (int nf = 0; nf < 4; ++nf) {
                int col = n0 + wn * 64 + nf * 16 + lr;
                if (col >= NPADo) continue;
                int hh = (o0 + wm * 64 + m * 16) >> 4;
                bool nok = (col < Nn);
                float v[4];
                #pragma unroll
                for (int r = 0; r < 4; ++r) {
                    int row = o0 + wm * 64 + m * 16 + kg * 4 + r;
                    float a = s[row];
                    v[r] = nok ? (acc[m][nf][r] * a + (bias[row] * a + off[row])) * pscale : 0.f;
                }
                unsigned h01 = cvt_pk_bf16(v[0], v[1]);
                unsigned h23 = cvt_pk_bf16(v[2], v[3]);
                float l0 = v[0] - __uint_as_float(h01 << 16);
                float l1 = v[1] - __uint_as_float(h01 & 0xffff0000u);
                float l2 = v[2] - __uint_as_float(h23 << 16);
                float l3 = v[3] - __uint_as_float(h23 & 0xffff0000u);
                uint2 hst = {h01, h23};
                uint2 lst = {cvt_pk_bf16(l0, l1), cvt_pk_bf16(l2, l3)};
                size_t base = ((size_t)(b * 8 + hh) * NPADo + col) * 32 + kg * 4;
                *(uint2*)(out_b + base)      = hst;
                *(uint2*)(out_b + base + 16) = lst;
            }
        }
    } else {
        #pragma unroll
        for (int nf = 0; nf < 4; ++nf) {
            int col_d = o0 + wn * 64 + nf * 16 + lr;
            float a = s[col_d];
            float badd = bias[col_d] * a + off[col_d];
            #pragma unroll
            for (int m = 0; m < 4; ++m) {
                int rown = n0 + wm * 64 + m * 16 + kg * 4;
                float v0 = acc[m][nf][0] * a + badd;
                float v1 = acc[m][nf][1] * a + badd;
                float v2 = acc[m][nf][2] * a + badd;
                float v3 = acc[m][nf][3] * a + badd;
                if (mode == 0) {
                    if (rown < Nn) {
                        float4 vv = {v0, v1, v2, v3};
                        *(float4*)(out_f + ((size_t)b * O + col_d) * Nn + rown) = vv;
                    }
                } else {
                    if (rown + 3 < NPADo) {
                        uint2 st = {cvt_pk_bf16(v0, v1), cvt_pk_bf16(v2, v3)};
                        *(uint2*)(out_b + ((size_t)b * O + col_d) * NPADo + rown) = st;
                    }
                }
            }
        }
    }
}

// ---------------- vlocalT: bn(dwconv) -> TRANSPOSED fp32 [b][196][512] ----------------
__global__ __launch_bounds__(256)
void vlocalT_kernel(const short* __restrict__ v,
                    const float* __restrict__ vl_w, const float* __restrict__ vl_b,
                    const float* __restrict__ vl_s, const float* __restrict__ vl_o,
                    float* __restrict__ vlT) {
    __shared__ float tile[32][201];
    const int cg = blockIdx.x, b = blockIdx.y;
    const int t = threadIdx.x;
    {
        const int c_l = t >> 3, nsub = t & 7;
        const int c = cg * 32 + c_l;
        const size_t base = ((size_t)b * DH + c) * KPAD;
        const float* w = vl_w + c * 9;
        const float w0 = w[0], w1 = w[1], w2 = w[2], w3 = w[3], w4 = w[4],
                    w5 = w[5], w6 = w[6], w7 = w[7], w8 = w[8];
        const float bias = vl_b[c], sc = vl_s[c], of = vl_o[c];
        for (int n2 = nsub; n2 < NN2; n2 += 8) {
            int i = n2 / RES2, j = n2 % RES2;
            int r0 = 2 * i - 1, c0 = 2 * j - 1;
            float acc = bias;
            if (r0 >= 0) {
                if (c0 >= 0)       acc += bf2f(v[base + r0 * RES + c0])     * w0;
                                   acc += bf2f(v[base + r0 * RES + c0 + 1]) * w1;
                if (c0 + 2 < RES)  acc += bf2f(v[base + r0 * RES + c0 + 2]) * w2;
            }
            {
                if (c0 >= 0)       acc += bf2f(v[base + (r0 + 1) * RES + c0])     * w3;
                                   acc += bf2f(v[base + (r0 + 1) * RES + c0 + 1]) * w4;
                if (c0 + 2 < RES)  acc += bf2f(v[base + (r0 + 1) * RES + c0 + 2]) * w5;
            }
            if (r0 + 2 < RES) {
                if (c0 >= 0)       acc += bf2f(v[base + (r0 + 2) * RES + c0])     * w6;
                                   acc += bf2f(v[base + (r0 + 2) * RES + c0 + 1]) * w7;
                if (c0 + 2 < RES)  acc += bf2f(v[base + (r0 + 2) * RES + c0 + 2]) * w8;
            }
            tile[c_l][n2] = acc * sc + of;
        }
    }
    __syncthreads();
    {
        const int c_l = t & 31, ng = t >> 5;
        for (int n2 = ng; n2 < NN2; n2 += 8)
            vlT[((size_t)b * NN2 + n2) * DH + cg * 32 + c_l] = tile[c_l][n2];
    }
}

// ---------------- bias expand: * log2e; pad keys = -inf (exp -> 0) ----------------
__global__ void biasB_expand_kernel(const float* __restrict__ ab, const int* __restrict__ bidx,
                                    short* __restrict__ biasB, int n_off) {
    int i = blockIdx.x * 256 + threadIdx.x;
    int h = blockIdx.y;
    if (i >= NN2 * KPAD) return;
    int q = i / KPAD, key = i - q * KPAD;
    short v = (short)0xFF80;    // bf16 -inf
    if (key < NN) v = f2bf(ab[h * n_off + bidx[q * NN + key]] * LOG2E);
    biasB[(size_t)h * NN2 * KPAD + i] = v;
}

// ---------------- MFMA attention v14 (reverted: best-known 59us version) ----------------
__global__ __launch_bounds__(512, 4)
void attn_mfma14_kernel(const short* __restrict__ QT, const short* __restrict__ KT,
                        const short* __restrict__ V, const short* __restrict__ biasB,
                        short* __restrict__ outT) {
    __shared__ __align__(1024) char LDS[2 * 12288 + 8 * 2048];

    const int t = threadIdx.x;
    const int bid = blockIdx.x;
    const int h = bid & 7;
    const int b = bid >> 3;

    const int lane = t & 63, wid = t >> 6;
    const int lr = lane & 15, kg = lane >> 4;
    const int wq0 = wid * 32;

    bf16x8 qb1[2], qb2[2];
    const short* bb[2];
    #pragma unroll
    for (int qf = 0; qf < 2; ++qf) {
        int qg = wq0 + qf * 16 + lr;
        const short* qrow = QT + ((size_t)(b * 8 + h) * QPAD + qg) * 32;
        qb1[qf] = *(const bf16x8*)(qrow + (kg & 1) * 8);
        qb2[qf] = (bf16x8){0, 0, 0, 0, 0, 0, 0, 0};
        if (kg < 2) qb2[qf] = *(const bf16x8*)(qrow + 16 + kg * 8);
        int qs = (qg < NN2) ? qg : (NN2 - 1);
        bb[qf] = biasB + ((size_t)h * NN2 + qs) * KPAD;
    }

    const short* kbase = KT + (size_t)(b * 8 + h) * KPAD * 32;
    const short* vbase = V + ((size_t)b * DH + h * DD) * KPAD;

    f32x4 acc[2][4];
    #pragma unroll
    for (int qf = 0; qf < 2; ++qf)
        #pragma unroll
        for (int nt = 0; nt < 4; ++nt)
            acc[qf][nt] = (f32x4){0.f, 0.f, 0.f, 0.f};
    float sacc[2] = {0.f, 0.f};
    char* PsW = LDS + 24576 + wid * 2048;
    const int swz = (lr & 7) << 4;

    auto STAGE = [&](int buf, int tile) {
        const int k0 = tile * 64;
        char* base = LDS + buf * 12288;
        #pragma unroll
        for (int ci = 0; ci < 2; ++ci) {
            if (ci == 1 && wid >= 4) continue;
            int chunk = (ci == 0) ? wid : wid + 8;
            if (chunk < 4) {
                int row = chunk * 16 + (lane >> 2);
                int pcol = (lane & 3) ^ ((row >> 1) & 3);
                gload16((const char*)(kbase + (size_t)(k0 + row) * 32) + pcol * 16,
                        base + chunk * 1024);
            } else {
                int vrow = (chunk - 4) * 8 + (lane >> 3);
                int pcol = (lane & 7) ^ (vrow & 7);
                gload16((const char*)(vbase + (size_t)vrow * KPAD + k0) + pcol * 16,
                        base + 4096 + (chunk - 4) * 1024);
            }
        }
    };

    auto COMPUTE = [&](int buf, int tile) {
        const int k0 = tile * 64;
        char* cb = LDS + buf * 12288;

        #pragma unroll
        for (int qf = 0; qf < 2; ++qf) {
            short4 b4[4];
            #pragma unroll
            for (int nt = 0; nt < 4; ++nt)
                b4[nt] = *(const short4*)(bb[qf] + k0 + nt * 16 + kg * 4);

            f32x4 sc[4];
            __builtin_amdgcn_s_setprio(1);
            #pragma unroll
            for (int nt = 0; nt < 4; ++nt) {
                int row = nt * 16 + lr;
                bf16x8 ka = *(const bf16x8*)(cb + row * 64 + ((kg ^ ((row >> 1) & 3)) * 16));
                sc[nt] = (f32x4){0.f, 0.f, 0.f, 0.f};
                sc[nt] = MFMA32(ka, qb1[qf], sc[nt]);
                sc[nt] = MFMA32(ka, qb2[qf], sc[nt]);
            }
            __builtin_amdgcn_s_setprio(0);

            #pragma unroll
            for (int nt = 0; nt < 4; ++nt) {
                float pv[4];
                #pragma unroll
                for (int r = 0; r < 4; ++r) {
                    float sv = sc[nt][r] + bf2f(((const short*)&b4[nt])[r]);
                    pv[r] = fexp2(sv);
                    sacc[qf] += pv[r];
                }
                uint2 pk2 = {cvt_pk_bf16(pv[0], pv[1]), cvt_pk_bf16(pv[2], pv[3])};
                *(uint2*)(PsW + lr * 128 + ((nt * 32 + kg * 8) ^ swz)) = pk2;
            }

            #pragma unroll
            for (int ks = 0; ks < 2; ++ks) {
                bf16x8 pa = *(const bf16x8*)(PsW + lr * 128 + ((ks * 64 + kg * 16) ^ swz));
                __builtin_amdgcn_s_setprio(1);
                #pragma unroll
                for (int nt = 0; nt < 4; ++nt) {
                    int row = nt * 16 + lr;
                    int pk_ = ks * 4 + kg;
                    bf16x8 vf = *(const bf16x8*)(cb + 4096 + row * 128 + ((pk_ ^ (row & 7)) * 16));
                    acc[qf][nt] = MFMA32(pa, vf, acc[qf][nt]);
                }
                __builtin_amdgcn_s_setprio(0);
            }
        }
    };

    STAGE(0, 0);
    int cur = 0;
    __syncthreads();
    #pragma unroll 1
    for (int tile = 0; tile < 13; ++tile) {
        if (tile + 1 < 13) STAGE(cur ^ 1, tile + 1);
        COMPUTE(cur, tile);
        __syncthreads();
        cur ^= 1;
    }

    #pragma unroll
    for (int qf = 0; qf < 2; ++qf) {
        float sv = sacc[qf];
        sv += __shfl_xor(sv, 16, 64);
        sv += __shfl_xor(sv, 32, 64);
        #pragma unroll
        for (int r = 0; r < 4; ++r) {
            int qrow_ = wq0 + qf * 16 + kg * 4 + r;
            if (qrow_ >= NN2) continue;
            float inv = 1.f / __shfl(sv, kg * 4 + r, 64);
            short* grow = outT + ((size_t)b * NN2 + qrow_) * DH + h * DD;
            #pragma unroll
            for (int nt = 0; nt < 4; ++nt) {
                int d = nt * 16 + lr;
                grow[d] = f2bf(acc[qf][nt][r] * inv);
            }
        }
    }
}

// ---------------- geluE: elementwise gelu(bf16 attnT + fp32 vlT) -> gT bf16 ----------------
__global__ __launch_bounds__(256)
void geluE_kernel(const short* __restrict__ aT, const float* __restrict__ vlT,
                  short* __restrict__ gT) {
    int i = blockIdx.x * 256 + threadIdx.x;
    int d0 = (i & 63) * 8;
    int n2 = (i >> 6) & (QPAD - 1);
    int b  = i >> 14;
    short* gp = gT + ((size_t)b * QPAD + n2) * DH + d0;
    if (n2 >= NN2) {
        *(uint4*)gp = (uint4){0u, 0u, 0u, 0u};
        return;
    }
    size_t ao = ((size_t)b * NN2 + n2) * DH + d0;
    bf16x8 av = *(const bf16x8*)(aT + ao);
    float4 v0 = *(const float4*)(vlT + ao);
    float4 v1 = *(const float4*)(vlT + ao + 4);
    float s[8];
    #pragma unroll
    for (int k = 0; k < 4; ++k) s[k] = bf2f(av[k]) + ((const float*)&v0)[k];
    #pragma unroll
    for (int k = 0; k < 4; ++k) s[4 + k] = bf2f(av[4 + k]) + ((const float*)&v1)[k];
    float g[8];
    #pragma unroll
    for (int k = 0; k < 8; ++k)
        g[k] = 0.5f * s[k] * (1.f + erff(s[k] * 0.70710678118654752440f));
    uint4 st = {cvt_pk_bf16(g[0], g[1]), cvt_pk_bf16(g[2], g[3]),
                cvt_pk_bf16(g[4], g[5]), cvt_pk_bf16(g[6], g[7])};
    *(uint4*)gp = st;
}

extern "C" void kernel_launch(void* const* d_in, const int* in_sizes, int n_in,
                              void* d_out, int out_size, void* d_ws, size_t ws_size,
                              hipStream_t stream) {
    const float* x     = (const float*)d_in[0];
    const float* ql_w  = (const float*)d_in[1];
    const float* ql_b  = (const float*)d_in[2];
    const float* qp_w  = (const float*)d_in[3];
    const float* qp_b  = (const float*)d_in[4];
    const float* qp_s  = (const float*)d_in[5];
    const float* qp_o  = (const float*)d_in[6];
    const float* k_w   = (const float*)d_in[7];
    const float* k_b   = (const float*)d_in[8];
    const float* k_s   = (const float*)d_in[9];
    const float* k_o   = (const float*)d_in[10];
    const float* v_w   = (const float*)d_in[11];
    const float* v_b   = (const float*)d_in[12];
    const float* v_s   = (const float*)d_in[13];
    const float* v_o   = (const float*)d_in[14];
    const float* vl_w  = (const float*)d_in[15];
    const float* vl_b  = (const float*)d_in[16];
    const float* vl_s  = (const float*)d_in[17];
    const float* vl_o  = (const float*)d_in[18];
    const float* p_w   = (const float*)d_in[19];
    const float* p_b   = (const float*)d_in[20];
    const float* p_s   = (const float*)d_in[21];
    const float* p_o   = (const float*)d_in[22];
    const float* ab    = (const float*)d_in[23];
    const int*   bidx  = (const int*)d_in[24];
    float* out = (float*)d_out;
    int n_off = in_sizes[23] / HEADS;

    char* ws = (char*)d_ws;
    short* qinT_h = (short*)(ws + O_QINT_HI);
    short* xT_h   = (short*)(ws + O_XT_HI);
    short* QT     = (short*)(ws + O_QT);
    short* KT     = (short*)(ws + O_KT);
    short* Vb     = (short*)(ws + O_V);
    float* vlT    = (float*)(ws + O_VLT);
    short* biasB  = (short*)(ws + O_BIASB);
    short* w_h    = (short*)(ws + O_W_HI);
    short* w_l    = (short*)(ws + O_W_LO);
    short* attnT  = (short*)(ws + O_ATTNT);
    short* gT_h   = (short*)(ws + O_GT_HI);

    // 1. xprep
    xprep_kernel<<<dim3(DIMC / 32, BATCH), 256, 0, stream>>>(x, ql_w, ql_b, xT_h, qinT_h);
    // 2. weight splits
    wsplit_kernel<<<dim3(1920), 256, 0, stream>>>(qp_w, k_w, v_w, p_w, w_h, w_l);
    // 3. q projection -> QT packed (pre-scaled by SCALE*log2e)
    gemm_split_kernel<false, false><<<dim3(128), 256, 0, stream>>>(
        w_h + 0, nullptr, qinT_h, qp_b, qp_s, qp_o,
        nullptr, QT, 2, DIMC, NN2, QPAD, QPAD, SCALE * LOG2E, 2, 1, 128);
    // 4. k projection -> KT packed
    gemm_split_kernel<false, false><<<dim3(448), 256, 0, stream>>>(
        w_h + 49152, nullptr, xT_h, k_b, k_s, k_o,
        nullptr, KT, 2, DIMC, NN, XPAD, KPAD, 1.0f, 7, 1, 128);
    // 5. v projection -> bf16, SWAPPED
    gemm_split_kernel<false, true><<<dim3(1792), 256, 0, stream>>>(
        w_h + 98304, nullptr, xT_h, v_b, v_s, v_o,
        nullptr, Vb, 1, DIMC, NN, XPAD, KPAD, 1.0f, 7, 4, 512);
    // 6. vlocalT (transposed fp32)
    vlocalT_kernel<<<dim3(DH / 32, BATCH), 256, 0, stream>>>(Vb, vl_w, vl_b, vl_s, vl_o, vlT);
    // 7. bias expand (log2e; pad keys -inf)
    biasB_expand_kernel<<<dim3((NN2 * KPAD + 255) / 256, HEADS), 256, 0, stream>>>(ab, bidx, biasB, n_off);
    // 8. attention -> attnT bf16 (v14, best-known)
    attn_mfma14_kernel<<<dim3(HEADS * BATCH), 512, 0, stream>>>(QT, KT, Vb, biasB, attnT);
    // 9. elementwise gelu -> gT bf16 (zero-fills pad rows)
    geluE_kernel<<<dim3(4096), 256, 0, stream>>>(attnT, vlT, gT_h);
    // 10. output projection, SWAPPED, single-term weights
    gemm_split_kernel<false, true><<<dim3(384), 256, 0, stream>>>(
        w_h + 294912, nullptr, gT_h, p_b, p_s, p_o,
        out, nullptr, 0, DH, NN2, QPAD, 0, 1.0f, 2, 3, 384);
}

// Round 29
// 255.942 us; speedup vs baseline: 1.0601x; 1.0170x over previous
//
#include <hip/hip_runtime.h>
#include <math.h>

#define BATCH   64
#define DIMC    384
#define KEY_DIM 16
#define HEADS   8
#define DD      64
#define DH      512
#define NH_KD   128
#define RES     28
#define RES2    14
#define NN      784
#define NN2     196
#define OUT_DIM 384
#define SCALE   0.25f
#define LOG2E   1.44269504088896340736f
#define XPAD    896     // 7*128
#define QPAD    256     // 2*128
#define KPAD    832     // 13*64
#define XSP     796     // xprep LDS pitch (shorts)

typedef __attribute__((ext_vector_type(8))) short bf16x8;
typedef __attribute__((ext_vector_type(4))) float f32x4;

#define MFMA32(a, b, c) __builtin_amdgcn_mfma_f32_16x16x32_bf16(a, b, c, 0, 0, 0)
#define SWZ(row, bcol) ((row) * 64 + ((bcol) ^ ((((row) >> 1) & 3) << 4)))

__device__ inline short f2bf(float f) {
    unsigned u = __float_as_uint(f);
    unsigned r = (u + 0x7fff + ((u >> 16) & 1)) >> 16;
    return (short)r;
}
__device__ inline float bf2f(short h) {
    return __uint_as_float(((unsigned)(unsigned short)h) << 16);
}
__device__ __forceinline__ unsigned cvt_pk_bf16(float a, float b) {
    unsigned r;
    asm("v_cvt_pk_bf16_f32 %0, %1, %2" : "=v"(r) : "v"(a), "v"(b));
    return r;
}
// raw HW 2^x (args pre-scaled by log2e); v_exp_f32(-inf) = 0 handles pad keys
__device__ __forceinline__ float fexp2(float x) {
    float r;
    asm("v_exp_f32 %0, %1" : "=v"(r) : "v"(x));
    return r;
}
__device__ __forceinline__ void gload16(const void* g, void* l) {
    __builtin_amdgcn_global_load_lds((const __attribute__((address_space(1))) void*)g,
                                     (__attribute__((address_space(3))) void*)l, 16, 0, 0);
}

// ---- ws byte offsets ----
#define O_XT_HI    0u
#define O_QINT_HI  44040192u
#define O_QT       88080384u
#define O_KT       96468992u
#define O_V        123731968u
#define O_VLT      178257920u   // fp32 [b][196][512] transposed vlocal
#define O_BIASB    203948032u
#define O_W_HI     206557184u
#define O_W_LO     207540224u
#define O_ATTNT    0u           // bf16 [b][196][512] (xT dead by attention)
#define O_GT_HI    25690112u    // bf16 [b][256][512]

// ---------------- xprep v2: fused x->xT + dwconv/pool -> qinT, short4-wide stores ----------------
__global__ __launch_bounds__(256)
void xprep_kernel(const float* __restrict__ x, const float* __restrict__ ql_w,
                  const float* __restrict__ ql_b, short* __restrict__ xT,
                  short* __restrict__ qinT) {
    __shared__ short xs[32 * XSP];
    const int cg = blockIdx.x, b = blockIdx.y;
    const int t = threadIdx.x;
    const float* xb = x + ((size_t)b * DIMC + cg * 32) * NN;

    // phase 0: coalesced x load -> bf16 LDS [c][n]
    {
        const int c = t >> 3, sub = t & 7;
        const float* xc = xb + (size_t)c * NN;
        short* dst = xs + c * XSP;
        #pragma unroll 5
        for (int p4 = sub; p4 < 196; p4 += 8) {
            float4 v = *(const float4*)(xc + p4 * 4);
            uint2 pk = {cvt_pk_bf16(v.x, v.y), cvt_pk_bf16(v.z, v.w)};
            *(uint2*)(dst + p4 * 4) = pk;
        }
    }
    __syncthreads();

    const int c4 = (t & 7) * 4;     // 4 channels per thread
    const int ng = t >> 3;          // 0..31

    // phase 1: transposed xT write, short4 per store (8 lanes -> 64B per row)
    {
        short* dstb = xT + (size_t)b * XPAD * DIMC + cg * 32 + c4;
        const short* s0 = xs + (c4 + 0) * XSP;
        const short* s1 = xs + (c4 + 1) * XSP;
        const short* s2 = xs + (c4 + 2) * XSP;
        const short* s3 = xs + (c4 + 3) * XSP;
        for (int n = ng; n < NN; n += 32) {
            short4 v = {s0[n], s1[n], s2[n], s3[n]};
            *(short4*)(dstb + (size_t)n * DIMC) = v;
        }
        const short4 z4 = {0, 0, 0, 0};
        for (int n = NN + ng; n < XPAD; n += 32)
            *(short4*)(dstb + (size_t)n * DIMC) = z4;
    }

    // phase 2: dwconv3x3 s2 (pad1) + pool for 4 channels -> qinT short4 stores
    {
        float wv[4][9], bi[4];
        #pragma unroll
        for (int j = 0; j < 4; ++j) {
            const int c = cg * 32 + c4 + j;
            #pragma unroll
            for (int k = 0; k < 9; ++k) wv[j][k] = ql_w[c * 9 + k];
            bi[j] = ql_b[c];
        }
        short* qdst = qinT + (size_t)b * QPAD * DIMC + cg * 32 + c4;
        for (int n2 = ng; n2 < NN2; n2 += 32) {
            int i = n2 / RES2, jj = n2 % RES2;
            int r0 = 2 * i - 1, cc0 = 2 * jj - 1;
            bool rt = (r0 >= 0), cl = (cc0 >= 0), cr = (cc0 + 2 < RES);
            short4 outv;
            #pragma unroll
            for (int j = 0; j < 4; ++j) {
                const short* xc = xs + (c4 + j) * XSP;
                float acc = bi[j];
                if (rt) {
                    if (cl) acc += bf2f(xc[r0 * RES + cc0])     * wv[j][0];
                            acc += bf2f(xc[r0 * RES + cc0 + 1]) * wv[j][1];
                    if (cr) acc += bf2f(xc[r0 * RES + cc0 + 2]) * wv[j][2];
                }
                {
                    if (cl) acc += bf2f(xc[(r0 + 1) * RES + cc0])     * wv[j][3];
                            acc += bf2f(xc[(r0 + 1) * RES + cc0 + 1]) * wv[j][4];
                    if (cr) acc += bf2f(xc[(r0 + 1) * RES + cc0 + 2]) * wv[j][5];
                }
                {
                    if (cl) acc += bf2f(xc[(r0 + 2) * RES + cc0])     * wv[j][6];
                            acc += bf2f(xc[(r0 + 2) * RES + cc0 + 1]) * wv[j][7];
                    if (cr) acc += bf2f(xc[(r0 + 2) * RES + cc0 + 2]) * wv[j][8];
                }
                acc += bf2f(xc[(2 * i) * RES + 2 * jj]);   // pool
                ((short*)&outv)[j] = f2bf(acc);
            }
            *(short4*)(qdst + (size_t)n2 * DIMC) = outv;
        }
        const short4 z4 = {0, 0, 0, 0};
        for (int n2 = NN2 + ng; n2 < QPAD; n2 += 32)
            *(short4*)(qdst + (size_t)n2 * DIMC) = z4;
    }
}

// ---------------- weight split ----------------
__global__ void wsplit_kernel(const float* __restrict__ w0, const float* __restrict__ w1,
                              const float* __restrict__ w2, const float* __restrict__ w3,
                              short* __restrict__ hi, short* __restrict__ lo) {
    int i = blockIdx.x * 256 + threadIdx.x;
    if (i >= 491520) return;
    const float* src; int j = i;
    if (j < 49152) src = w0;
    else if (j < 98304) { src = w1; j -= 49152; }
    else if (j < 294912) { src = w2; j -= 98304; }
    else { src = w3; j -= 294912; }
    float v = src[j];
    short h = f2bf(v);
    hi[i] = h;
    lo[i] = f2bf(v - bf2f(h));
}

// ---------------- bf16 MFMA GEMM (unchanged) ----------------
template<bool WLO, bool SWAP>
__global__ __launch_bounds__(256)
void gemm_split_kernel(const short* __restrict__ wgt_hi, const short* __restrict__ wgt_lo,
                       const short* __restrict__ act,
                       const float* __restrict__ bias, const float* __restrict__ s,
                       const float* __restrict__ off,
                       float* __restrict__ out_f, short* __restrict__ out_b,
                       int mode, int C, int Nn, int Npad, int NPADo, float pscale,
                       int NXn, int NYo, int O) {
    constexpr int NT = 2 + (WLO ? 1 : 0);
    constexpr int STRIDE = NT * 8192;
    constexpr int OFF_A = 0, OFF_B = 8192, OFF_WL = 16384;
    __shared__ __align__(1024) char LDS[2 * STRIDE];

    const int bid = blockIdx.x;
    const int xcd = bid & 7;
    const int g   = bid >> 3;
    const int ot  = g % NYo;
    const int pp  = (g / NYo) * 8 + xcd;
    const int nt  = pp % NXn;
    const int b   = pp / NXn;
    const int n0 = nt * 128, o0 = ot * 128;

    const int t = threadIdx.x;
    const int lane = t & 63, wid = t >> 6;
    const int wm = wid & 1, wn = wid >> 1;
    const int lr = lane & 15, kg = lane >> 4;

    const short* Ahi = SWAP ? act : wgt_hi;
    const short* Bhi = SWAP ? wgt_hi : act;

    f32x4 acc[4][4];
    #pragma unroll
    for (int m = 0; m < 4; ++m)
        #pragma unroll
        for (int n = 0; n < 4; ++n)
            acc[m][n] = (f32x4){0.f, 0.f, 0.f, 0.f};

    const int ccol = (lane & 3) * 16;
    const int r0   = wid * 32 + (lane >> 2);

    auto STAGE = [&](int buf, int k0) {
        char* base = LDS + buf * STRIDE;
        #pragma unroll
        for (int c = 0; c < 2; ++c) {
            int r = r0 + c * 16;
            int bcs = ccol ^ (((r >> 1) & 3) << 4);
            size_t aRow = SWAP ? ((size_t)b * Npad + n0 + r) : (size_t)(o0 + r);
            size_t bRow = SWAP ? (size_t)(o0 + r) : ((size_t)b * Npad + n0 + r);
            char* ldsc = base + wid * 2048 + c * 1024;
            gload16((const char*)Ahi + (aRow * C + k0) * 2 + bcs, ldsc + OFF_A);
            gload16((const char*)Bhi + (bRow * C + k0) * 2 + bcs, ldsc + OFF_B);
            if constexpr (WLO)
                gload16((const char*)wgt_lo + ((size_t)(o0 + r) * C + k0) * 2 + bcs, ldsc + OFF_WL);
        }
    };

    STAGE(0, 0);
    int cur = 0;
    __syncthreads();

    for (int k0 = 0;; k0 += 32) {
        const bool hasNext = (k0 + 32 < C);
        if (hasNext) STAGE(cur ^ 1, k0 + 32);

        char* cb = LDS + cur * STRIDE;
        bf16x8 ah[4], wlm[4];
        #pragma unroll
        for (int m = 0; m < 4; ++m) {
            int row = wm * 64 + m * 16 + lr;
            ah[m] = *(const bf16x8*)(cb + OFF_A + SWZ(row, kg * 16));
            if constexpr (WLO) if (!SWAP) wlm[m] = *(const bf16x8*)(cb + OFF_WL + SWZ(row, kg * 16));
        }
        #pragma unroll
        for (int nf = 0; nf < 4; ++nf) {
            int row = wn * 64 + nf * 16 + lr;
            bf16x8 bh = *(const bf16x8*)(cb + OFF_B + SWZ(row, kg * 16));
            bf16x8 blw;
            if constexpr (WLO) if (SWAP) blw = *(const bf16x8*)(cb + OFF_WL + SWZ(row, kg * 16));
            #pragma unroll
            for (int m = 0; m < 4; ++m) {
                acc[m][nf] = MFMA32(ah[m], bh, acc[m][nf]);
                if constexpr (WLO) {
                    if (SWAP) acc[m][nf] = MFMA32(ah[m], blw, acc[m][nf]);
                    else      acc[m][nf] = MFMA32(wlm[m], bh, acc[m][nf]);
                }
            }
        }
        if (!hasNext) break;
        __syncthreads();
        cur ^= 1;
    }

    if (mode == 2) {
        #pragma unroll
        for (int m = 0; m < 4; ++m) {
            #pragma unroll
            for (int nf = 0; nf < 4; ++nf) {
                int col = n0 + wn * 64 + nf * 16 + lr;
                if (col >= NPADo) continue;
                int hh = (o0 + wm * 64 + m * 16) >> 4;
                bool nok = (col < Nn);
                float v[4];
                #pragma unroll
                for (int r = 0; r < 4; ++r) {
                    int row = o0 + wm * 64 + m * 16 + kg * 4 + r;
                    float a = s[row];
                    v[r] = nok ? (acc[m][nf][r] * a + (bias[row] * a + off[row])) * pscale : 0.f;
                }
                unsigned h01 = cvt_pk_bf16(v[0], v[1]);
                unsigned h23 = cvt_pk_bf16(v[2], v[3]);
                float l0 = v[0] - __uint_as_float(h01 << 16);
                float l1 = v[1] - __uint_as_float(h01 & 0xffff0000u);
                float l2 = v[2] - __uint_as_float(h23 << 16);
                float l3 = v[3] - __uint_as_float(h23 & 0xffff0000u);
                uint2 hst = {h01, h23};
                uint2 lst = {cvt_pk_bf16(l0, l1), cvt_pk_bf16(l2, l3)};
                size_t base = ((size_t)(b * 8 + hh) * NPADo + col) * 32 + kg * 4;
                *(uint2*)(out_b + base)      = hst;
                *(uint2*)(out_b + base + 16) = lst;
            }
        }
    } else {
        #pragma unroll
        for (int nf = 0; nf < 4; ++nf) {
            int col_d = o0 + wn * 64 + nf * 16 + lr;
            float a = s[col_d];
            float badd = bias[col_d] * a + off[col_d];
            #pragma unroll
            for (int m = 0; m < 4; ++m) {
                int rown = n0 + wm * 64 + m * 16 + kg * 4;
                float v0 = acc[m][nf][0] * a + badd;
                float v1 = acc[m][nf][1] * a + badd;
                float v2 = acc[m][nf][2] * a + badd;
                float v3 = acc[m][nf][3] * a + badd;
                if (mode == 0) {
                    if (rown < Nn) {
                        float4 vv = {v0, v1, v2, v3};
                        *(float4*)(out_f + ((size_t)b * O + col_d) * Nn + rown) = vv;
                    }
                } else {
                    if (rown + 3 < NPADo) {
                        uint2 st = {cvt_pk_bf16(v0, v1), cvt_pk_bf16(v2, v3)};
                        *(uint2*)(out_b + ((size_t)b * O + col_d) * NPADo + rown) = st;
                    }
                }
            }
        }
    }
}

// ---------------- vlocalT: bn(dwconv) -> TRANSPOSED fp32 [b][196][512] ----------------
__global__ __launch_bounds__(256)
void vlocalT_kernel(const short* __restrict__ v,
                    const float* __restrict__ vl_w, const float* __restrict__ vl_b,
                    const float* __restrict__ vl_s, const float* __restrict__ vl_o,
                    float* __restrict__ vlT) {
    __shared__ float tile[32][201];
    const int cg = blockIdx.x, b = blockIdx.y;
    const int t = threadIdx.x;
    {
        const int c_l = t >> 3, nsub = t & 7;
        const int c = cg * 32 + c_l;
        const size_t base = ((size_t)b * DH + c) * KPAD;
        const float* w = vl_w + c * 9;
        const float w0 = w[0], w1 = w[1], w2 = w[2], w3 = w[3], w4 = w[4],
                    w5 = w[5], w6 = w[6], w7 = w[7], w8 = w[8];
        const float bias = vl_b[c], sc = vl_s[c], of = vl_o[c];
        for (int n2 = nsub; n2 < NN2; n2 += 8) {
            int i = n2 / RES2, j = n2 % RES2;
            int r0 = 2 * i - 1, c0 = 2 * j - 1;
            float acc = bias;
            if (r0 >= 0) {
                if (c0 >= 0)       acc += bf2f(v[base + r0 * RES + c0])     * w0;
                                   acc += bf2f(v[base + r0 * RES + c0 + 1]) * w1;
                if (c0 + 2 < RES)  acc += bf2f(v[base + r0 * RES + c0 + 2]) * w2;
            }
            {
                if (c0 >= 0)       acc += bf2f(v[base + (r0 + 1) * RES + c0])     * w3;
                                   acc += bf2f(v[base + (r0 + 1) * RES + c0 + 1]) * w4;
                if (c0 + 2 < RES)  acc += bf2f(v[base + (r0 + 1) * RES + c0 + 2]) * w5;
            }
            if (r0 + 2 < RES) {
                if (c0 >= 0)       acc += bf2f(v[base + (r0 + 2) * RES + c0])     * w6;
                                   acc += bf2f(v[base + (r0 + 2) * RES + c0 + 1]) * w7;
                if (c0 + 2 < RES)  acc += bf2f(v[base + (r0 + 2) * RES + c0 + 2]) * w8;
            }
            tile[c_l][n2] = acc * sc + of;
        }
    }
    __syncthreads();
    {
        const int c_l = t & 31, ng = t >> 5;
        for (int n2 = ng; n2 < NN2; n2 += 8)
            vlT[((size_t)b * NN2 + n2) * DH + cg * 32 + c_l] = tile[c_l][n2];
    }
}

// ---------------- bias expand: * log2e; pad keys = -inf (exp -> 0) ----------------
__global__ void biasB_expand_kernel(const float* __restrict__ ab, const int* __restrict__ bidx,
                                    short* __restrict__ biasB, int n_off) {
    int i = blockIdx.x * 256 + threadIdx.x;
    int h = blockIdx.y;
    if (i >= NN2 * KPAD) return;
    int q = i / KPAD, key = i - q * KPAD;
    short v = (short)0xFF80;    // bf16 -inf
    if (key < NN) v = f2bf(ab[h * n_off + bidx[q * NN + key]] * LOG2E);
    biasB[(size_t)h * NN2 * KPAD + i] = v;
}

// ---------------- MFMA attention v16: v14 + dead-q-wave compute skip ----------------
__global__ __launch_bounds__(512, 4)
void attn_mfma16_kernel(const short* __restrict__ QT, const short* __restrict__ KT,
                        const short* __restrict__ V, const short* __restrict__ biasB,
                        short* __restrict__ outT) {
    __shared__ __align__(1024) char LDS[2 * 12288 + 8 * 2048];

    const int t = threadIdx.x;
    const int bid = blockIdx.x;
    const int h = bid & 7;
    const int b = bid >> 3;

    const int lane = t & 63, wid = t >> 6;
    const int lr = lane & 15, kg = lane >> 4;
    const int wq0 = wid * 32;

    bf16x8 qb1[2], qb2[2];
    const short* bb[2];
    #pragma unroll
    for (int qf = 0; qf < 2; ++qf) {
        int qg = wq0 + qf * 16 + lr;
        const short* qrow = QT + ((size_t)(b * 8 + h) * QPAD + qg) * 32;
        qb1[qf] = *(const bf16x8*)(qrow + (kg & 1) * 8);
        qb2[qf] = (bf16x8){0, 0, 0, 0, 0, 0, 0, 0};
        if (kg < 2) qb2[qf] = *(const bf16x8*)(qrow + 16 + kg * 8);
        int qs = (qg < NN2) ? qg : (NN2 - 1);
        bb[qf] = biasB + ((size_t)h * NN2 + qs) * KPAD;
    }

    const short* kbase = KT + (size_t)(b * 8 + h) * KPAD * 32;
    const short* vbase = V + ((size_t)b * DH + h * DD) * KPAD;

    f32x4 acc[2][4];
    #pragma unroll
    for (int qf = 0; qf < 2; ++qf)
        #pragma unroll
        for (int nt = 0; nt < 4; ++nt)
            acc[qf][nt] = (f32x4){0.f, 0.f, 0.f, 0.f};
    float sacc[2] = {0.f, 0.f};
    char* PsW = LDS + 24576 + wid * 2048;
    const int swz = (lr & 7) << 4;

    auto STAGE = [&](int buf, int tile) {
        const int k0 = tile * 64;
        char* base = LDS + buf * 12288;
        #pragma unroll
        for (int ci = 0; ci < 2; ++ci) {
            if (ci == 1 && wid >= 4) continue;
            int chunk = (ci == 0) ? wid : wid + 8;
            if (chunk < 4) {
                int row = chunk * 16 + (lane >> 2);
                int pcol = (lane & 3) ^ ((row >> 1) & 3);
                gload16((const char*)(kbase + (size_t)(k0 + row) * 32) + pcol * 16,
                        base + chunk * 1024);
            } else {
                int vrow = (chunk - 4) * 8 + (lane >> 3);
                int pcol = (lane & 7) ^ (vrow & 7);
                gload16((const char*)(vbase + (size_t)vrow * KPAD + k0) + pcol * 16,
                        base + 4096 + (chunk - 4) * 1024);
            }
        }
    };

    auto COMPUTE = [&](int buf, int tile) {
        const int k0 = tile * 64;
        char* cb = LDS + buf * 12288;

        #pragma unroll
        for (int qf = 0; qf < 2; ++qf) {
            // dead-q skip: wave-uniform guard (wave 7 skips both qf, wave 6 skips qf=1);
            // saves 3/16 of all MFMA+exp work per block. sacc stays 0; epilogue rows guarded.
            if (wq0 + qf * 16 >= NN2) continue;

            short4 b4[4];
            #pragma unroll
            for (int nt = 0; nt < 4; ++nt)
                b4[nt] = *(const short4*)(bb[qf] + k0 + nt * 16 + kg * 4);

            f32x4 sc[4];
            __builtin_amdgcn_s_setprio(1);
            #pragma unroll
            for (int nt = 0; nt < 4; ++nt) {
                int row = nt * 16 + lr;
                bf16x8 ka = *(const bf16x8*)(cb + row * 64 + ((kg ^ ((row >> 1) & 3)) * 16));
                sc[nt] = (f32x4){0.f, 0.f, 0.f, 0.f};
                sc[nt] = MFMA32(ka, qb1[qf], sc[nt]);
                sc[nt] = MFMA32(ka, qb2[qf], sc[nt]);
            }
            __builtin_amdgcn_s_setprio(0);

            #pragma unroll
            for (int nt = 0; nt < 4; ++nt) {
                float pv[4];
                #pragma unroll
                for (int r = 0; r < 4; ++r) {
                    float sv = sc[nt][r] + bf2f(((const short*)&b4[nt])[r]);
                    pv[r] = fexp2(sv);
                    sacc[qf] += pv[r];
                }
                uint2 pk2 = {cvt_pk_bf16(pv[0], pv[1]), cvt_pk_bf16(pv[2], pv[3])};
                *(uint2*)(PsW + lr * 128 + ((nt * 32 + kg * 8) ^ swz)) = pk2;
            }

            #pragma unroll
            for (int ks = 0; ks < 2; ++ks) {
                bf16x8 pa = *(const bf16x8*)(PsW + lr * 128 + ((ks * 64 + kg * 16) ^ swz));
                __builtin_amdgcn_s_setprio(1);
                #pragma unroll
                for (int nt = 0; nt < 4; ++nt) {
                    int row = nt * 16 + lr;
                    int pk_ = ks * 4 + kg;
                    bf16x8 vf = *(const bf16x8*)(cb + 4096 + row * 128 + ((pk_ ^ (row & 7)) * 16));
                    acc[qf][nt] = MFMA32(pa, vf, acc[qf][nt]);
                }
                __builtin_amdgcn_s_setprio(0);
            }
        }
    };

    STAGE(0, 0);
    int cur = 0;
    __syncthreads();
    #pragma unroll 1
    for (int tile = 0; tile < 13; ++tile) {
        if (tile + 1 < 13) STAGE(cur ^ 1, tile + 1);
        COMPUTE(cur, tile);
        __syncthreads();
        cur ^= 1;
    }

    #pragma unroll
    for (int qf = 0; qf < 2; ++qf) {
        float sv = sacc[qf];
        sv += __shfl_xor(sv, 16, 64);
        sv += __shfl_xor(sv, 32, 64);
        #pragma unroll
        for (int r = 0; r < 4; ++r) {
            int qrow_ = wq0 + qf * 16 + kg * 4 + r;
            if (qrow_ >= NN2) continue;
            float inv = 1.f / __shfl(sv, kg * 4 + r, 64);
            short* grow = outT + ((size_t)b * NN2 + qrow_) * DH + h * DD;
            #pragma unroll
            for (int nt = 0; nt < 4; ++nt) {
                int d = nt * 16 + lr;
                grow[d] = f2bf(acc[qf][nt][r] * inv);
            }
        }
    }
}

// ---------------- geluE: elementwise gelu(bf16 attnT + fp32 vlT) -> gT bf16 ----------------
__global__ __launch_bounds__(256)
void geluE_kernel(const short* __restrict__ aT, const float* __restrict__ vlT,
                  short* __restrict__ gT) {
    int i = blockIdx.x * 256 + threadIdx.x;
    int d0 = (i & 63) * 8;
    int n2 = (i >> 6) & (QPAD - 1);
    int b  = i >> 14;
    short* gp = gT + ((size_t)b * QPAD + n2) * DH + d0;
    if (n2 >= NN2) {
        *(uint4*)gp = (uint4){0u, 0u, 0u, 0u};
        return;
    }
    size_t ao = ((size_t)b * NN2 + n2) * DH + d0;
    bf16x8 av = *(const bf16x8*)(aT + ao);
    float4 v0 = *(const float4*)(vlT + ao);
    float4 v1 = *(const float4*)(vlT + ao + 4);
    float s[8];
    #pragma unroll
    for (int k = 0; k < 4; ++k) s[k] = bf2f(av[k]) + ((const float*)&v0)[k];
    #pragma unroll
    for (int k = 0; k < 4; ++k) s[4 + k] = bf2f(av[4 + k]) + ((const float*)&v1)[k];
    float g[8];
    #pragma unroll
    for (int k = 0; k < 8; ++k)
        g[k] = 0.5f * s[k] * (1.f + erff(s[k] * 0.70710678118654752440f));
    uint4 st = {cvt_pk_bf16(g[0], g[1]), cvt_pk_bf16(g[2], g[3]),
                cvt_pk_bf16(g[4], g[5]), cvt_pk_bf16(g[6], g[7])};
    *(uint4*)gp = st;
}

extern "C" void kernel_launch(void* const* d_in, const int* in_sizes, int n_in,
                              void* d_out, int out_size, void* d_ws, size_t ws_size,
                              hipStream_t stream) {
    const float* x     = (const float*)d_in[0];
    const float* ql_w  = (const float*)d_in[1];
    const float* ql_b  = (const float*)d_in[2];
    const float* qp_w  = (const float*)d_in[3];
    const float* qp_b  = (const float*)d_in[4];
    const float* qp_s  = (const float*)d_in[5];
    const float* qp_o  = (const float*)d_in[6];
    const float* k_w   = (const float*)d_in[7];
    const float* k_b   = (const float*)d_in[8];
    const float* k_s   = (const float*)d_in[9];
    const float* k_o   = (const float*)d_in[10];
    const float* v_w   = (const float*)d_in[11];
    const float* v_b   = (const float*)d_in[12];
    const float* v_s   = (const float*)d_in[13];
    const float* v_o   = (const float*)d_in[14];
    const float* vl_w  = (const float*)d_in[15];
    const float* vl_b  = (const float*)d_in[16];
    const float* vl_s  = (const float*)d_in[17];
    const float* vl_o  = (const float*)d_in[18];
    const float* p_w   = (const float*)d_in[19];
    const float* p_b   = (const float*)d_in[20];
    const float* p_s   = (const float*)d_in[21];
    const float* p_o   = (const float*)d_in[22];
    const float* ab    = (const float*)d_in[23];
    const int*   bidx  = (const int*)d_in[24];
    float* out = (float*)d_out;
    int n_off = in_sizes[23] / HEADS;

    char* ws = (char*)d_ws;
    short* qinT_h = (short*)(ws + O_QINT_HI);
    short* xT_h   = (short*)(ws + O_XT_HI);
    short* QT     = (short*)(ws + O_QT);
    short* KT     = (short*)(ws + O_KT);
    short* Vb     = (short*)(ws + O_V);
    float* vlT    = (float*)(ws + O_VLT);
    short* biasB  = (short*)(ws + O_BIASB);
    short* w_h    = (short*)(ws + O_W_HI);
    short* w_l    = (short*)(ws + O_W_LO);
    short* attnT  = (short*)(ws + O_ATTNT);
    short* gT_h   = (short*)(ws + O_GT_HI);

    // 1. xprep
    xprep_kernel<<<dim3(DIMC / 32, BATCH), 256, 0, stream>>>(x, ql_w, ql_b, xT_h, qinT_h);
    // 2. weight splits
    wsplit_kernel<<<dim3(1920), 256, 0, stream>>>(qp_w, k_w, v_w, p_w, w_h, w_l);
    // 3. q projection -> QT packed (pre-scaled by SCALE*log2e)
    gemm_split_kernel<false, false><<<dim3(128), 256, 0, stream>>>(
        w_h + 0, nullptr, qinT_h, qp_b, qp_s, qp_o,
        nullptr, QT, 2, DIMC, NN2, QPAD, QPAD, SCALE * LOG2E, 2, 1, 128);
    // 4. k projection -> KT packed
    gemm_split_kernel<false, false><<<dim3(448), 256, 0, stream>>>(
        w_h + 49152, nullptr, xT_h, k_b, k_s, k_o,
        nullptr, KT, 2, DIMC, NN, XPAD, KPAD, 1.0f, 7, 1, 128);
    // 5. v projection -> bf16, SWAPPED
    gemm_split_kernel<false, true><<<dim3(1792), 256, 0, stream>>>(
        w_h + 98304, nullptr, xT_h, v_b, v_s, v_o,
        nullptr, Vb, 1, DIMC, NN, XPAD, KPAD, 1.0f, 7, 4, 512);
    // 6. vlocalT (transposed fp32)
    vlocalT_kernel<<<dim3(DH / 32, BATCH), 256, 0, stream>>>(Vb, vl_w, vl_b, vl_s, vl_o, vlT);
    // 7. bias expand (log2e; pad keys -inf)
    biasB_expand_kernel<<<dim3((NN2 * KPAD + 255) / 256, HEADS), 256, 0, stream>>>(ab, bidx, biasB, n_off);
    // 8. attention -> attnT bf16 (v16: dead-q compute skip)
    attn_mfma16_kernel<<<dim3(HEADS * BATCH), 512, 0, stream>>>(QT, KT, Vb, biasB, attnT);
    // 9. elementwise gelu -> gT bf16 (zero-fills pad rows)
    geluE_kernel<<<dim3(4096), 256, 0, stream>>>(attnT, vlT, gT_h);
    // 10. output projection, SWAPPED, single-term weights
    gemm_split_kernel<false, true><<<dim3(384), 256, 0, stream>>>(
        w_h + 294912, nullptr, gT_h, p_b, p_s, p_o,
        out, nullptr, 0, DH, NN2, QPAD, 0, 1.0f, 2, 3, 384);
}

// Round 30
// 254.688 us; speedup vs baseline: 1.0654x; 1.0049x over previous
//
#include <hip/hip_runtime.h>
#include <math.h>

#define BATCH   64
#define DIMC    384
#define KEY_DIM 16
#define HEADS   8
#define DD      64
#define DH      512
#define NH_KD   128
#define RES     28
#define RES2    14
#define NN      784
#define NN2     196
#define OUT_DIM 384
#define SCALE   0.25f
#define LOG2E   1.44269504088896340736f
#define XPAD    896     // 7*128
#define QPAD    256     // 2*128
#define KPAD    832     // 13*64
#define XSP     796     // xprep LDS pitch (shorts)

typedef __attribute__((ext_vector_type(8))) short bf16x8;
typedef __attribute__((ext_vector_type(4))) float f32x4;

#define MFMA32(a, b, c) __builtin_amdgcn_mfma_f32_16x16x32_bf16(a, b, c, 0, 0, 0)
#define SWZ(row, bcol) ((row) * 64 + ((bcol) ^ ((((row) >> 1) & 3) << 4)))

__device__ inline short f2bf(float f) {
    unsigned u = __float_as_uint(f);
    unsigned r = (u + 0x7fff + ((u >> 16) & 1)) >> 16;
    return (short)r;
}
__device__ inline float bf2f(short h) {
    return __uint_as_float(((unsigned)(unsigned short)h) << 16);
}
__device__ __forceinline__ unsigned cvt_pk_bf16(float a, float b) {
    unsigned r;
    asm("v_cvt_pk_bf16_f32 %0, %1, %2" : "=v"(r) : "v"(a), "v"(b));
    return r;
}
// raw HW 2^x (args pre-scaled by log2e); v_exp_f32(-inf) = 0 handles pad keys
__device__ __forceinline__ float fexp2(float x) {
    float r;
    asm("v_exp_f32 %0, %1" : "=v"(r) : "v"(x));
    return r;
}
__device__ __forceinline__ void gload16(const void* g, void* l) {
    __builtin_amdgcn_global_load_lds((const __attribute__((address_space(1))) void*)g,
                                     (__attribute__((address_space(3))) void*)l, 16, 0, 0);
}

// ---- ws byte offsets ----
#define O_XT_HI    0u
#define O_QINT_HI  44040192u
#define O_QT       88080384u
#define O_KT       96468992u
#define O_V        123731968u
#define O_VLT      178257920u   // fp32 [b][196][512] transposed vlocal
#define O_BIASB    203948032u
#define O_W_HI     206557184u
#define O_W_LO     207540224u
#define O_ATTNT    0u           // bf16 [b][196][512] (xT dead by attention)
#define O_GT_HI    25690112u    // bf16 [b][256][512]

// ---------------- xprep v3: 16 channels/block (25.5KB LDS -> 6 blocks/CU, 2x TLP) ----------------
__global__ __launch_bounds__(256)
void xprep_kernel(const float* __restrict__ x, const float* __restrict__ ql_w,
                  const float* __restrict__ ql_b, short* __restrict__ xT,
                  short* __restrict__ qinT) {
    __shared__ short xs[16 * XSP];
    const int cg = blockIdx.x, b = blockIdx.y;   // cg: 0..23 (16-channel groups)
    const int t = threadIdx.x;
    const float* xb = x + ((size_t)b * DIMC + cg * 16) * NN;

    // phase 0: coalesced x load -> bf16 LDS [c][n]; 16 threads per channel
    {
        const int c = t >> 4, sub = t & 15;
        const float* xc = xb + (size_t)c * NN;
        short* dst = xs + c * XSP;
        #pragma unroll 4
        for (int p4 = sub; p4 < 196; p4 += 16) {
            float4 v = *(const float4*)(xc + p4 * 4);
            uint2 pk = {cvt_pk_bf16(v.x, v.y), cvt_pk_bf16(v.z, v.w)};
            *(uint2*)(dst + p4 * 4) = pk;
        }
    }
    __syncthreads();

    const int c4 = (t & 3) * 4;     // 4 channels per thread (16 per 4-thread group)
    const int ng = t >> 2;          // 0..63

    // phase 1: transposed xT write, short4 per store (4 lanes -> 32B per row)
    {
        short* dstb = xT + (size_t)b * XPAD * DIMC + cg * 16 + c4;
        const short* s0 = xs + (c4 + 0) * XSP;
        const short* s1 = xs + (c4 + 1) * XSP;
        const short* s2 = xs + (c4 + 2) * XSP;
        const short* s3 = xs + (c4 + 3) * XSP;
        for (int n = ng; n < NN; n += 64) {
            short4 v = {s0[n], s1[n], s2[n], s3[n]};
            *(short4*)(dstb + (size_t)n * DIMC) = v;
        }
        const short4 z4 = {0, 0, 0, 0};
        for (int n = NN + ng; n < XPAD; n += 64)
            *(short4*)(dstb + (size_t)n * DIMC) = z4;
    }

    // phase 2: dwconv3x3 s2 (pad1) + pool for 4 channels -> qinT short4 stores
    {
        float wv[4][9], bi[4];
        #pragma unroll
        for (int j = 0; j < 4; ++j) {
            const int c = cg * 16 + c4 + j;
            #pragma unroll
            for (int k = 0; k < 9; ++k) wv[j][k] = ql_w[c * 9 + k];
            bi[j] = ql_b[c];
        }
        short* qdst = qinT + (size_t)b * QPAD * DIMC + cg * 16 + c4;
        for (int n2 = ng; n2 < NN2; n2 += 64) {
            int i = n2 / RES2, jj = n2 % RES2;
            int r0 = 2 * i - 1, cc0 = 2 * jj - 1;
            bool rt = (r0 >= 0), cl = (cc0 >= 0), cr = (cc0 + 2 < RES);
            short4 outv;
            #pragma unroll
            for (int j = 0; j < 4; ++j) {
                const short* xc = xs + (c4 + j) * XSP;
                float acc = bi[j];
                if (rt) {
                    if (cl) acc += bf2f(xc[r0 * RES + cc0])     * wv[j][0];
                            acc += bf2f(xc[r0 * RES + cc0 + 1]) * wv[j][1];
                    if (cr) acc += bf2f(xc[r0 * RES + cc0 + 2]) * wv[j][2];
                }
                {
                    if (cl) acc += bf2f(xc[(r0 + 1) * RES + cc0])     * wv[j][3];
                            acc += bf2f(xc[(r0 + 1) * RES + cc0 + 1]) * wv[j][4];
                    if (cr) acc += bf2f(xc[(r0 + 1) * RES + cc0 + 2]) * wv[j][5];
                }
                {
                    if (cl) acc += bf2f(xc[(r0 + 2) * RES + cc0])     * wv[j][6];
                            acc += bf2f(xc[(r0 + 2) * RES + cc0 + 1]) * wv[j][7];
                    if (cr) acc += bf2f(xc[(r0 + 2) * RES + cc0 + 2]) * wv[j][8];
                }
                acc += bf2f(xc[(2 * i) * RES + 2 * jj]);   // pool
                ((short*)&outv)[j] = f2bf(acc);
            }
            *(short4*)(qdst + (size_t)n2 * DIMC) = outv;
        }
        const short4 z4 = {0, 0, 0, 0};
        for (int n2 = NN2 + ng; n2 < QPAD; n2 += 64)
            *(short4*)(qdst + (size_t)n2 * DIMC) = z4;
    }
}

// ---------------- weight split ----------------
__global__ void wsplit_kernel(const float* __restrict__ w0, const float* __restrict__ w1,
                              const float* __restrict__ w2, const float* __restrict__ w3,
                              short* __restrict__ hi, short* __restrict__ lo) {
    int i = blockIdx.x * 256 + threadIdx.x;
    if (i >= 491520) return;
    const float* src; int j = i;
    if (j < 49152) src = w0;
    else if (j < 98304) { src = w1; j -= 49152; }
    else if (j < 294912) { src = w2; j -= 98304; }
    else { src = w3; j -= 294912; }
    float v = src[j];
    short h = f2bf(v);
    hi[i] = h;
    lo[i] = f2bf(v - bf2f(h));
}

// ---------------- bf16 MFMA GEMM (unchanged) ----------------
template<bool WLO, bool SWAP>
__global__ __launch_bounds__(256)
void gemm_split_kernel(const short* __restrict__ wgt_hi, const short* __restrict__ wgt_lo,
                       const short* __restrict__ act,
                       const float* __restrict__ bias, const float* __restrict__ s,
                       const float* __restrict__ off,
                       float* __restrict__ out_f, short* __restrict__ out_b,
                       int mode, int C, int Nn, int Npad, int NPADo, float pscale,
                       int NXn, int NYo, int O) {
    constexpr int NT = 2 + (WLO ? 1 : 0);
    constexpr int STRIDE = NT * 8192;
    constexpr int OFF_A = 0, OFF_B = 8192, OFF_WL = 16384;
    __shared__ __align__(1024) char LDS[2 * STRIDE];

    const int bid = blockIdx.x;
    const int xcd = bid & 7;
    const int g   = bid >> 3;
    const int ot  = g % NYo;
    const int pp  = (g / NYo) * 8 + xcd;
    const int nt  = pp % NXn;
    const int b   = pp / NXn;
    const int n0 = nt * 128, o0 = ot * 128;

    const int t = threadIdx.x;
    const int lane = t & 63, wid = t >> 6;
    const int wm = wid & 1, wn = wid >> 1;
    const int lr = lane & 15, kg = lane >> 4;

    const short* Ahi = SWAP ? act : wgt_hi;
    const short* Bhi = SWAP ? wgt_hi : act;

    f32x4 acc[4][4];
    #pragma unroll
    for (int m = 0; m < 4; ++m)
        #pragma unroll
        for (int n = 0; n < 4; ++n)
            acc[m][n] = (f32x4){0.f, 0.f, 0.f, 0.f};

    const int ccol = (lane & 3) * 16;
    const int r0   = wid * 32 + (lane >> 2);

    auto STAGE = [&](int buf, int k0) {
        char* base = LDS + buf * STRIDE;
        #pragma unroll
        for (int c = 0; c < 2; ++c) {
            int r = r0 + c * 16;
            int bcs = ccol ^ (((r >> 1) & 3) << 4);
            size_t aRow = SWAP ? ((size_t)b * Npad + n0 + r) : (size_t)(o0 + r);
            size_t bRow = SWAP ? (size_t)(o0 + r) : ((size_t)b * Npad + n0 + r);
            char* ldsc = base + wid * 2048 + c * 1024;
            gload16((const char*)Ahi + (aRow * C + k0) * 2 + bcs, ldsc + OFF_A);
            gload16((const char*)Bhi + (bRow * C + k0) * 2 + bcs, ldsc + OFF_B);
            if constexpr (WLO)
                gload16((const char*)wgt_lo + ((size_t)(o0 + r) * C + k0) * 2 + bcs, ldsc + OFF_WL);
        }
    };

    STAGE(0, 0);
    int cur = 0;
    __syncthreads();

    for (int k0 = 0;; k0 += 32) {
        const bool hasNext = (k0 + 32 < C);
        if (hasNext) STAGE(cur ^ 1, k0 + 32);

        char* cb = LDS + cur * STRIDE;
        bf16x8 ah[4], wlm[4];
        #pragma unroll
        for (int m = 0; m < 4; ++m) {
            int row = wm * 64 + m * 16 + lr;
            ah[m] = *(const bf16x8*)(cb + OFF_A + SWZ(row, kg * 16));
            if constexpr (WLO) if (!SWAP) wlm[m] = *(const bf16x8*)(cb + OFF_WL + SWZ(row, kg * 16));
        }
        #pragma unroll
        for (int nf = 0; nf < 4; ++nf) {
            int row = wn * 64 + nf * 16 + lr;
            bf16x8 bh = *(const bf16x8*)(cb + OFF_B + SWZ(row, kg * 16));
            bf16x8 blw;
            if constexpr (WLO) if (SWAP) blw = *(const bf16x8*)(cb + OFF_WL + SWZ(row, kg * 16));
            #pragma unroll
            for (int m = 0; m < 4; ++m) {
                acc[m][nf] = MFMA32(ah[m], bh, acc[m][nf]);
                if constexpr (WLO) {
                    if (SWAP) acc[m][nf] = MFMA32(ah[m], blw, acc[m][nf]);
                    else      acc[m][nf] = MFMA32(wlm[m], bh, acc[m][nf]);
                }
            }
        }
        if (!hasNext) break;
        __syncthreads();
        cur ^= 1;
    }

    if (mode == 2) {
        #pragma unroll
        for (int m = 0; m < 4; ++m) {
            #pragma unroll
            for (int nf = 0; nf < 4; ++nf) {
                int col = n0 + wn * 64 + nf * 16 + lr;
                if (col >= NPADo) continue;
                int hh = (o0 + wm * 64 + m * 16) >> 4;
                bool nok = (col < Nn);
                float v[4];
                #pragma unroll
                for (int r = 0; r < 4; ++r) {
                    int row = o0 + wm * 64 + m * 16 + kg * 4 + r;
                    float a = s[row];
                    v[r] = nok ? (acc[m][nf][r] * a + (bias[row] * a + off[row])) * pscale : 0.f;
                }
                unsigned h01 = cvt_pk_bf16(v[0], v[1]);
                unsigned h23 = cvt_pk_bf16(v[2], v[3]);
                float l0 = v[0] - __uint_as_float(h01 << 16);
                float l1 = v[1] - __uint_as_float(h01 & 0xffff0000u);
                float l2 = v[2] - __uint_as_float(h23 << 16);
                float l3 = v[3] - __uint_as_float(h23 & 0xffff0000u);
                uint2 hst = {h01, h23};
                uint2 lst = {cvt_pk_bf16(l0, l1), cvt_pk_bf16(l2, l3)};
                size_t base = ((size_t)(b * 8 + hh) * NPADo + col) * 32 + kg * 4;
                *(uint2*)(out_b + base)      = hst;
                *(uint2*)(out_b + base + 16) = lst;
            }
        }
    } else {
        #pragma unroll
        for (int nf = 0; nf < 4; ++nf) {
            int col_d = o0 + wn * 64 + nf * 16 + lr;
            float a = s[col_d];
            float badd = bias[col_d] * a + off[col_d];
            #pragma unroll
            for (int m = 0; m < 4; ++m) {
                int rown = n0 + wm * 64 + m * 16 + kg * 4;
                float v0 = acc[m][nf][0] * a + badd;
                float v1 = acc[m][nf][1] * a + badd;
                float v2 = acc[m][nf][2] * a + badd;
                float v3 = acc[m][nf][3] * a + badd;
                if (mode == 0) {
                    if (rown < Nn) {
                        float4 vv = {v0, v1, v2, v3};
                        *(float4*)(out_f + ((size_t)b * O + col_d) * Nn + rown) = vv;
                    }
                } else {
                    if (rown + 3 < NPADo) {
                        uint2 st = {cvt_pk_bf16(v0, v1), cvt_pk_bf16(v2, v3)};
                        *(uint2*)(out_b + ((size_t)b * O + col_d) * NPADo + rown) = st;
                    }
                }
            }
        }
    }
}

// ---------------- vlocalT: bn(dwconv) -> TRANSPOSED fp32 [b][196][512] ----------------
__global__ __launch_bounds__(256)
void vlocalT_kernel(const short* __restrict__ v,
                    const float* __restrict__ vl_w, const float* __restrict__ vl_b,
                    const float* __restrict__ vl_s, const float* __restrict__ vl_o,
                    float* __restrict__ vlT) {
    __shared__ float tile[32][201];
    const int cg = blockIdx.x, b = blockIdx.y;
    const int t = threadIdx.x;
    {
        const int c_l = t >> 3, nsub = t & 7;
        const int c = cg * 32 + c_l;
        const size_t base = ((size_t)b * DH + c) * KPAD;
        const float* w = vl_w + c * 9;
        const float w0 = w[0], w1 = w[1], w2 = w[2], w3 = w[3], w4 = w[4],
                    w5 = w[5], w6 = w[6], w7 = w[7], w8 = w[8];
        const float bias = vl_b[c], sc = vl_s[c], of = vl_o[c];
        for (int n2 = nsub; n2 < NN2; n2 += 8) {
            int i = n2 / RES2, j = n2 % RES2;
            int r0 = 2 * i - 1, c0 = 2 * j - 1;
            float acc = bias;
            if (r0 >= 0) {
                if (c0 >= 0)       acc += bf2f(v[base + r0 * RES + c0])     * w0;
                                   acc += bf2f(v[base + r0 * RES + c0 + 1]) * w1;
                if (c0 + 2 < RES)  acc += bf2f(v[base + r0 * RES + c0 + 2]) * w2;
            }
            {
                if (c0 >= 0)       acc += bf2f(v[base + (r0 + 1) * RES + c0])     * w3;
                                   acc += bf2f(v[base + (r0 + 1) * RES + c0 + 1]) * w4;
                if (c0 + 2 < RES)  acc += bf2f(v[base + (r0 + 1) * RES + c0 + 2]) * w5;
            }
            if (r0 + 2 < RES) {
                if (c0 >= 0)       acc += bf2f(v[base + (r0 + 2) * RES + c0])     * w6;
                                   acc += bf2f(v[base + (r0 + 2) * RES + c0 + 1]) * w7;
                if (c0 + 2 < RES)  acc += bf2f(v[base + (r0 + 2) * RES + c0 + 2]) * w8;
            }
            tile[c_l][n2] = acc * sc + of;
        }
    }
    __syncthreads();
    {
        const int c_l = t & 31, ng = t >> 5;
        for (int n2 = ng; n2 < NN2; n2 += 8)
            vlT[((size_t)b * NN2 + n2) * DH + cg * 32 + c_l] = tile[c_l][n2];
    }
}

// ---------------- bias expand: * log2e; pad keys = -inf (exp -> 0) ----------------
__global__ void biasB_expand_kernel(const float* __restrict__ ab, const int* __restrict__ bidx,
                                    short* __restrict__ biasB, int n_off) {
    int i = blockIdx.x * 256 + threadIdx.x;
    int h = blockIdx.y;
    if (i >= NN2 * KPAD) return;
    int q = i / KPAD, key = i - q * KPAD;
    short v = (short)0xFF80;    // bf16 -inf
    if (key < NN) v = f2bf(ab[h * n_off + bidx[q * NN + key]] * LOG2E);
    biasB[(size_t)h * NN2 * KPAD + i] = v;
}

// ---------------- MFMA attention v16 (unchanged from R29) ----------------
__global__ __launch_bounds__(512, 4)
void attn_mfma16_kernel(const short* __restrict__ QT, const short* __restrict__ KT,
                        const short* __restrict__ V, const short* __restrict__ biasB,
                        short* __restrict__ outT) {
    __shared__ __align__(1024) char LDS[2 * 12288 + 8 * 2048];

    const int t = threadIdx.x;
    const int bid = blockIdx.x;
    const int h = bid & 7;
    const int b = bid >> 3;

    const int lane = t & 63, wid = t >> 6;
    const int lr = lane & 15, kg = lane >> 4;
    const int wq0 = wid * 32;

    bf16x8 qb1[2], qb2[2];
    const short* bb[2];
    #pragma unroll
    for (int qf = 0; qf < 2; ++qf) {
        int qg = wq0 + qf * 16 + lr;
        const short* qrow = QT + ((size_t)(b * 8 + h) * QPAD + qg) * 32;
        qb1[qf] = *(const bf16x8*)(qrow + (kg & 1) * 8);
        qb2[qf] = (bf16x8){0, 0, 0, 0, 0, 0, 0, 0};
        if (kg < 2) qb2[qf] = *(const bf16x8*)(qrow + 16 + kg * 8);
        int qs = (qg < NN2) ? qg : (NN2 - 1);
        bb[qf] = biasB + ((size_t)h * NN2 + qs) * KPAD;
    }

    const short* kbase = KT + (size_t)(b * 8 + h) * KPAD * 32;
    const short* vbase = V + ((size_t)b * DH + h * DD) * KPAD;

    f32x4 acc[2][4];
    #pragma unroll
    for (int qf = 0; qf < 2; ++qf)
        #pragma unroll
        for (int nt = 0; nt < 4; ++nt)
            acc[qf][nt] = (f32x4){0.f, 0.f, 0.f, 0.f};
    float sacc[2] = {0.f, 0.f};
    char* PsW = LDS + 24576 + wid * 2048;
    const int swz = (lr & 7) << 4;

    auto STAGE = [&](int buf, int tile) {
        const int k0 = tile * 64;
        char* base = LDS + buf * 12288;
        #pragma unroll
        for (int ci = 0; ci < 2; ++ci) {
            if (ci == 1 && wid >= 4) continue;
            int chunk = (ci == 0) ? wid : wid + 8;
            if (chunk < 4) {
                int row = chunk * 16 + (lane >> 2);
                int pcol = (lane & 3) ^ ((row >> 1) & 3);
                gload16((const char*)(kbase + (size_t)(k0 + row) * 32) + pcol * 16,
                        base + chunk * 1024);
            } else {
                int vrow = (chunk - 4) * 8 + (lane >> 3);
                int pcol = (lane & 7) ^ (vrow & 7);
                gload16((const char*)(vbase + (size_t)vrow * KPAD + k0) + pcol * 16,
                        base + 4096 + (chunk - 4) * 1024);
            }
        }
    };

    auto COMPUTE = [&](int buf, int tile) {
        const int k0 = tile * 64;
        char* cb = LDS + buf * 12288;

        #pragma unroll
        for (int qf = 0; qf < 2; ++qf) {
            if (wq0 + qf * 16 >= NN2) continue;   // dead-q wave-uniform skip

            short4 b4[4];
            #pragma unroll
            for (int nt = 0; nt < 4; ++nt)
                b4[nt] = *(const short4*)(bb[qf] + k0 + nt * 16 + kg * 4);

            f32x4 sc[4];
            __builtin_amdgcn_s_setprio(1);
            #pragma unroll
            for (int nt = 0; nt < 4; ++nt) {
                int row = nt * 16 + lr;
                bf16x8 ka = *(const bf16x8*)(cb + row * 64 + ((kg ^ ((row >> 1) & 3)) * 16));
                sc[nt] = (f32x4){0.f, 0.f, 0.f, 0.f};
                sc[nt] = MFMA32(ka, qb1[qf], sc[nt]);
                sc[nt] = MFMA32(ka, qb2[qf], sc[nt]);
            }
            __builtin_amdgcn_s_setprio(0);

            #pragma unroll
            for (int nt = 0; nt < 4; ++nt) {
                float pv[4];
                #pragma unroll
                for (int r = 0; r < 4; ++r) {
                    float sv = sc[nt][r] + bf2f(((const short*)&b4[nt])[r]);
                    pv[r] = fexp2(sv);
                    sacc[qf] += pv[r];
                }
                uint2 pk2 = {cvt_pk_bf16(pv[0], pv[1]), cvt_pk_bf16(pv[2], pv[3])};
                *(uint2*)(PsW + lr * 128 + ((nt * 32 + kg * 8) ^ swz)) = pk2;
            }

            #pragma unroll
            for (int ks = 0; ks < 2; ++ks) {
                bf16x8 pa = *(const bf16x8*)(PsW + lr * 128 + ((ks * 64 + kg * 16) ^ swz));
                __builtin_amdgcn_s_setprio(1);
                #pragma unroll
                for (int nt = 0; nt < 4; ++nt) {
                    int row = nt * 16 + lr;
                    int pk_ = ks * 4 + kg;
                    bf16x8 vf = *(const bf16x8*)(cb + 4096 + row * 128 + ((pk_ ^ (row & 7)) * 16));
                    acc[qf][nt] = MFMA32(pa, vf, acc[qf][nt]);
                }
                __builtin_amdgcn_s_setprio(0);
            }
        }
    };

    STAGE(0, 0);
    int cur = 0;
    __syncthreads();
    #pragma unroll 1
    for (int tile = 0; tile < 13; ++tile) {
        if (tile + 1 < 13) STAGE(cur ^ 1, tile + 1);
        COMPUTE(cur, tile);
        __syncthreads();
        cur ^= 1;
    }

    #pragma unroll
    for (int qf = 0; qf < 2; ++qf) {
        float sv = sacc[qf];
        sv += __shfl_xor(sv, 16, 64);
        sv += __shfl_xor(sv, 32, 64);
        #pragma unroll
        for (int r = 0; r < 4; ++r) {
            int qrow_ = wq0 + qf * 16 + kg * 4 + r;
            if (qrow_ >= NN2) continue;
            float inv = 1.f / __shfl(sv, kg * 4 + r, 64);
            short* grow = outT + ((size_t)b * NN2 + qrow_) * DH + h * DD;
            #pragma unroll
            for (int nt = 0; nt < 4; ++nt) {
                int d = nt * 16 + lr;
                grow[d] = f2bf(acc[qf][nt][r] * inv);
            }
        }
    }
}

// ---------------- geluE: elementwise gelu(bf16 attnT + fp32 vlT) -> gT bf16 ----------------
__global__ __launch_bounds__(256)
void geluE_kernel(const short* __restrict__ aT, const float* __restrict__ vlT,
                  short* __restrict__ gT) {
    int i = blockIdx.x * 256 + threadIdx.x;
    int d0 = (i & 63) * 8;
    int n2 = (i >> 6) & (QPAD - 1);
    int b  = i >> 14;
    short* gp = gT + ((size_t)b * QPAD + n2) * DH + d0;
    if (n2 >= NN2) {
        *(uint4*)gp = (uint4){0u, 0u, 0u, 0u};
        return;
    }
    size_t ao = ((size_t)b * NN2 + n2) * DH + d0;
    bf16x8 av = *(const bf16x8*)(aT + ao);
    float4 v0 = *(const float4*)(vlT + ao);
    float4 v1 = *(const float4*)(vlT + ao + 4);
    float s[8];
    #pragma unroll
    for (int k = 0; k < 4; ++k) s[k] = bf2f(av[k]) + ((const float*)&v0)[k];
    #pragma unroll
    for (int k = 0; k < 4; ++k) s[4 + k] = bf2f(av[4 + k]) + ((const float*)&v1)[k];
    float g[8];
    #pragma unroll
    for (int k = 0; k < 8; ++k)
        g[k] = 0.5f * s[k] * (1.f + erff(s[k] * 0.70710678118654752440f));
    uint4 st = {cvt_pk_bf16(g[0], g[1]), cvt_pk_bf16(g[2], g[3]),
                cvt_pk_bf16(g[4], g[5]), cvt_pk_bf16(g[6], g[7])};
    *(uint4*)gp = st;
}

extern "C" void kernel_launch(void* const* d_in, const int* in_sizes, int n_in,
                              void* d_out, int out_size, void* d_ws, size_t ws_size,
                              hipStream_t stream) {
    const float* x     = (const float*)d_in[0];
    const float* ql_w  = (const float*)d_in[1];
    const float* ql_b  = (const float*)d_in[2];
    const float* qp_w  = (const float*)d_in[3];
    const float* qp_b  = (const float*)d_in[4];
    const float* qp_s  = (const float*)d_in[5];
    const float* qp_o  = (const float*)d_in[6];
    const float* k_w   = (const float*)d_in[7];
    const float* k_b   = (const float*)d_in[8];
    const float* k_s   = (const float*)d_in[9];
    const float* k_o   = (const float*)d_in[10];
    const float* v_w   = (const float*)d_in[11];
    const float* v_b   = (const float*)d_in[12];
    const float* v_s   = (const float*)d_in[13];
    const float* v_o   = (const float*)d_in[14];
    const float* vl_w  = (const float*)d_in[15];
    const float* vl_b  = (const float*)d_in[16];
    const float* vl_s  = (const float*)d_in[17];
    const float* vl_o  = (const float*)d_in[18];
    const float* p_w   = (const float*)d_in[19];
    const float* p_b   = (const float*)d_in[20];
    const float* p_s   = (const float*)d_in[21];
    const float* p_o   = (const float*)d_in[22];
    const float* ab    = (const float*)d_in[23];
    const int*   bidx  = (const int*)d_in[24];
    float* out = (float*)d_out;
    int n_off = in_sizes[23] / HEADS;

    char* ws = (char*)d_ws;
    short* qinT_h = (short*)(ws + O_QINT_HI);
    short* xT_h   = (short*)(ws + O_XT_HI);
    short* QT     = (short*)(ws + O_QT);
    short* KT     = (short*)(ws + O_KT);
    short* Vb     = (short*)(ws + O_V);
    float* vlT    = (float*)(ws + O_VLT);
    short* biasB  = (short*)(ws + O_BIASB);
    short* w_h    = (short*)(ws + O_W_HI);
    short* w_l    = (short*)(ws + O_W_LO);
    short* attnT  = (short*)(ws + O_ATTNT);
    short* gT_h   = (short*)(ws + O_GT_HI);

    // 1. xprep (16 channels/block, 6 blocks/CU)
    xprep_kernel<<<dim3(DIMC / 16, BATCH), 256, 0, stream>>>(x, ql_w, ql_b, xT_h, qinT_h);
    // 2. weight splits
    wsplit_kernel<<<dim3(1920), 256, 0, stream>>>(qp_w, k_w, v_w, p_w, w_h, w_l);
    // 3. q projection -> QT packed (pre-scaled by SCALE*log2e)
    gemm_split_kernel<false, false><<<dim3(128), 256, 0, stream>>>(
        w_h + 0, nullptr, qinT_h, qp_b, qp_s, qp_o,
        nullptr, QT, 2, DIMC, NN2, QPAD, QPAD, SCALE * LOG2E, 2, 1, 128);
    // 4. k projection -> KT packed
    gemm_split_kernel<false, false><<<dim3(448), 256, 0, stream>>>(
        w_h + 49152, nullptr, xT_h, k_b, k_s, k_o,
        nullptr, KT, 2, DIMC, NN, XPAD, KPAD, 1.0f, 7, 1, 128);
    // 5. v projection -> bf16, SWAPPED
    gemm_split_kernel<false, true><<<dim3(1792), 256, 0, stream>>>(
        w_h + 98304, nullptr, xT_h, v_b, v_s, v_o,
        nullptr, Vb, 1, DIMC, NN, XPAD, KPAD, 1.0f, 7, 4, 512);
    // 6. vlocalT (transposed fp32)
    vlocalT_kernel<<<dim3(DH / 32, BATCH), 256, 0, stream>>>(Vb, vl_w, vl_b, vl_s, vl_o, vlT);
    // 7. bias expand (log2e; pad keys -inf)
    biasB_expand_kernel<<<dim3((NN2 * KPAD + 255) / 256, HEADS), 256, 0, stream>>>(ab, bidx, biasB, n_off);
    // 8. attention -> attnT bf16 (v16)
    attn_mfma16_kernel<<<dim3(HEADS * BATCH), 512, 0, stream>>>(QT, KT, Vb, biasB, attnT);
    // 9. elementwise gelu -> gT bf16 (zero-fills pad rows)
    geluE_kernel<<<dim3(4096), 256, 0, stream>>>(attnT, vlT, gT_h);
    // 10. output projection, SWAPPED, single-term weights
    gemm_split_kernel<false, true><<<dim3(384), 256, 0, stream>>>(
        w_h + 294912, nullptr, gT_h, p_b, p_s, p_o,
        out, nullptr, 0, DH, NN2, QPAD, 0, 1.0f, 2, 3, 384);
}

// Round 31
// 251.897 us; speedup vs baseline: 1.0772x; 1.0111x over previous
//
#include <hip/hip_runtime.h>
#include <math.h>

#define BATCH   64
#define DIMC    384
#define KEY_DIM 16
#define HEADS   8
#define DD      64
#define DH      512
#define NH_KD   128
#define RES     28
#define RES2    14
#define NN      784
#define NN2     196
#define OUT_DIM 384
#define SCALE   0.25f
#define LOG2E   1.44269504088896340736f
#define XPAD    896     // 7*128
#define QPAD    256     // 2*128
#define KPAD    832     // 13*64
#define XSP     796     // xprep LDS pitch (shorts)

typedef __attribute__((ext_vector_type(8))) short bf16x8;
typedef __attribute__((ext_vector_type(4))) float f32x4;

#define MFMA32(a, b, c) __builtin_amdgcn_mfma_f32_16x16x32_bf16(a, b, c, 0, 0, 0)
#define SWZ(row, bcol) ((row) * 64 + ((bcol) ^ ((((row) >> 1) & 3) << 4)))

__device__ inline short f2bf(float f) {
    unsigned u = __float_as_uint(f);
    unsigned r = (u + 0x7fff + ((u >> 16) & 1)) >> 16;
    return (short)r;
}
__device__ inline float bf2f(short h) {
    return __uint_as_float(((unsigned)(unsigned short)h) << 16);
}
__device__ __forceinline__ unsigned cvt_pk_bf16(float a, float b) {
    unsigned r;
    asm("v_cvt_pk_bf16_f32 %0, %1, %2" : "=v"(r) : "v"(a), "v"(b));
    return r;
}
// raw HW 2^x (args pre-scaled by log2e); v_exp_f32(-inf) = 0 handles pad keys
__device__ __forceinline__ float fexp2(float x) {
    float r;
    asm("v_exp_f32 %0, %1" : "=v"(r) : "v"(x));
    return r;
}
__device__ __forceinline__ void gload16(const void* g, void* l) {
    __builtin_amdgcn_global_load_lds((const __attribute__((address_space(1))) void*)g,
                                     (__attribute__((address_space(3))) void*)l, 16, 0, 0);
}

// ---- ws byte offsets ----
#define O_XT_HI    0u
#define O_QINT_HI  44040192u
#define O_QT       88080384u
#define O_KT       96468992u
#define O_V        123731968u
#define O_BIASB    203948032u
#define O_W_HI     206557184u
#define O_W_LO     207540224u
#define O_ATTNT    0u           // bf16 [b][196][512] (xT dead by attention)
#define O_GT_HI    25690112u    // bf16 [b][256][512]

// ---------------- xprep v3: 16 channels/block (unchanged from R30) ----------------
__global__ __launch_bounds__(256)
void xprep_kernel(const float* __restrict__ x, const float* __restrict__ ql_w,
                  const float* __restrict__ ql_b, short* __restrict__ xT,
                  short* __restrict__ qinT) {
    __shared__ short xs[16 * XSP];
    const int cg = blockIdx.x, b = blockIdx.y;
    const int t = threadIdx.x;
    const float* xb = x + ((size_t)b * DIMC + cg * 16) * NN;

    {
        const int c = t >> 4, sub = t & 15;
        const float* xc = xb + (size_t)c * NN;
        short* dst = xs + c * XSP;
        #pragma unroll 4
        for (int p4 = sub; p4 < 196; p4 += 16) {
            float4 v = *(const float4*)(xc + p4 * 4);
            uint2 pk = {cvt_pk_bf16(v.x, v.y), cvt_pk_bf16(v.z, v.w)};
            *(uint2*)(dst + p4 * 4) = pk;
        }
    }
    __syncthreads();

    const int c4 = (t & 3) * 4;
    const int ng = t >> 2;

    {
        short* dstb = xT + (size_t)b * XPAD * DIMC + cg * 16 + c4;
        const short* s0 = xs + (c4 + 0) * XSP;
        const short* s1 = xs + (c4 + 1) * XSP;
        const short* s2 = xs + (c4 + 2) * XSP;
        const short* s3 = xs + (c4 + 3) * XSP;
        for (int n = ng; n < NN; n += 64) {
            short4 v = {s0[n], s1[n], s2[n], s3[n]};
            *(short4*)(dstb + (size_t)n * DIMC) = v;
        }
        const short4 z4 = {0, 0, 0, 0};
        for (int n = NN + ng; n < XPAD; n += 64)
            *(short4*)(dstb + (size_t)n * DIMC) = z4;
    }

    {
        float wv[4][9], bi[4];
        #pragma unroll
        for (int j = 0; j < 4; ++j) {
            const int c = cg * 16 + c4 + j;
            #pragma unroll
            for (int k = 0; k < 9; ++k) wv[j][k] = ql_w[c * 9 + k];
            bi[j] = ql_b[c];
        }
        short* qdst = qinT + (size_t)b * QPAD * DIMC + cg * 16 + c4;
        for (int n2 = ng; n2 < NN2; n2 += 64) {
            int i = n2 / RES2, jj = n2 % RES2;
            int r0 = 2 * i - 1, cc0 = 2 * jj - 1;
            bool rt = (r0 >= 0), cl = (cc0 >= 0), cr = (cc0 + 2 < RES);
            short4 outv;
            #pragma unroll
            for (int j = 0; j < 4; ++j) {
                const short* xc = xs + (c4 + j) * XSP;
                float acc = bi[j];
                if (rt) {
                    if (cl) acc += bf2f(xc[r0 * RES + cc0])     * wv[j][0];
                            acc += bf2f(xc[r0 * RES + cc0 + 1]) * wv[j][1];
                    if (cr) acc += bf2f(xc[r0 * RES + cc0 + 2]) * wv[j][2];
                }
                {
                    if (cl) acc += bf2f(xc[(r0 + 1) * RES + cc0])     * wv[j][3];
                            acc += bf2f(xc[(r0 + 1) * RES + cc0 + 1]) * wv[j][4];
                    if (cr) acc += bf2f(xc[(r0 + 1) * RES + cc0 + 2]) * wv[j][5];
                }
                {
                    if (cl) acc += bf2f(xc[(r0 + 2) * RES + cc0])     * wv[j][6];
                            acc += bf2f(xc[(r0 + 2) * RES + cc0 + 1]) * wv[j][7];
                    if (cr) acc += bf2f(xc[(r0 + 2) * RES + cc0 + 2]) * wv[j][8];
                }
                acc += bf2f(xc[(2 * i) * RES + 2 * jj]);   // pool
                ((short*)&outv)[j] = f2bf(acc);
            }
            *(short4*)(qdst + (size_t)n2 * DIMC) = outv;
        }
        const short4 z4 = {0, 0, 0, 0};
        for (int n2 = NN2 + ng; n2 < QPAD; n2 += 64)
            *(short4*)(qdst + (size_t)n2 * DIMC) = z4;
    }
}

// ---------------- weight split ----------------
__global__ void wsplit_kernel(const float* __restrict__ w0, const float* __restrict__ w1,
                              const float* __restrict__ w2, const float* __restrict__ w3,
                              short* __restrict__ hi, short* __restrict__ lo) {
    int i = blockIdx.x * 256 + threadIdx.x;
    if (i >= 491520) return;
    const float* src; int j = i;
    if (j < 49152) src = w0;
    else if (j < 98304) { src = w1; j -= 49152; }
    else if (j < 294912) { src = w2; j -= 98304; }
    else { src = w3; j -= 294912; }
    float v = src[j];
    short h = f2bf(v);
    hi[i] = h;
    lo[i] = f2bf(v - bf2f(h));
}

// ---------------- bf16 MFMA GEMM (unchanged) ----------------
template<bool WLO, bool SWAP>
__global__ __launch_bounds__(256)
void gemm_split_kernel(const short* __restrict__ wgt_hi, const short* __restrict__ wgt_lo,
                       const short* __restrict__ act,
                       const float* __restrict__ bias, const float* __restrict__ s,
                       const float* __restrict__ off,
                       float* __restrict__ out_f, short* __restrict__ out_b,
                       int mode, int C, int Nn, int Npad, int NPADo, float pscale,
                       int NXn, int NYo, int O) {
    constexpr int NT = 2 + (WLO ? 1 : 0);
    constexpr int STRIDE = NT * 8192;
    constexpr int OFF_A = 0, OFF_B = 8192, OFF_WL = 16384;
    __shared__ __align__(1024) char LDS[2 * STRIDE];

    const int bid = blockIdx.x;
    const int xcd = bid & 7;
    const int g   = bid >> 3;
    const int ot  = g % NYo;
    const int pp  = (g / NYo) * 8 + xcd;
    const int nt  = pp % NXn;
    const int b   = pp / NXn;
    const int n0 = nt * 128, o0 = ot * 128;

    const int t = threadIdx.x;
    const int lane = t & 63, wid = t >> 6;
    const int wm = wid & 1, wn = wid >> 1;
    const int lr = lane & 15, kg = lane >> 4;

    const short* Ahi = SWAP ? act : wgt_hi;
    const short* Bhi = SWAP ? wgt_hi : act;

    f32x4 acc[4][4];
    #pragma unroll
    for (int m = 0; m < 4; ++m)
        #pragma unroll
        for (int n = 0; n < 4; ++n)
            acc[m][n] = (f32x4){0.f, 0.f, 0.f, 0.f};

    const int ccol = (lane & 3) * 16;
    const int r0   = wid * 32 + (lane >> 2);

    auto STAGE = [&](int buf, int k0) {
        char* base = LDS + buf * STRIDE;
        #pragma unroll
        for (int c = 0; c < 2; ++c) {
            int r = r0 + c * 16;
            int bcs = ccol ^ (((r >> 1) & 3) << 4);
            size_t aRow = SWAP ? ((size_t)b * Npad + n0 + r) : (size_t)(o0 + r);
            size_t bRow = SWAP ? (size_t)(o0 + r) : ((size_t)b * Npad + n0 + r);
            char* ldsc = base + wid * 2048 + c * 1024;
            gload16((const char*)Ahi + (aRow * C + k0) * 2 + bcs, ldsc + OFF_A);
            gload16((const char*)Bhi + (bRow * C + k0) * 2 + bcs, ldsc + OFF_B);
            if constexpr (WLO)
                gload16((const char*)wgt_lo + ((size_t)(o0 + r) * C + k0) * 2 + bcs, ldsc + OFF_WL);
        }
    };

    STAGE(0, 0);
    int cur = 0;
    __syncthreads();

    for (int k0 = 0;; k0 += 32) {
        const bool hasNext = (k0 + 32 < C);
        if (hasNext) STAGE(cur ^ 1, k0 + 32);

        char* cb = LDS + cur * STRIDE;
        bf16x8 ah[4], wlm[4];
        #pragma unroll
        for (int m = 0; m < 4; ++m) {
            int row = wm * 64 + m * 16 + lr;
            ah[m] = *(const bf16x8*)(cb + OFF_A + SWZ(row, kg * 16));
            if constexpr (WLO) if (!SWAP) wlm[m] = *(const bf16x8*)(cb + OFF_WL + SWZ(row, kg * 16));
        }
        #pragma unroll
        for (int nf = 0; nf < 4; ++nf) {
            int row = wn * 64 + nf * 16 + lr;
            bf16x8 bh = *(const bf16x8*)(cb + OFF_B + SWZ(row, kg * 16));
            bf16x8 blw;
            if constexpr (WLO) if (SWAP) blw = *(const bf16x8*)(cb + OFF_WL + SWZ(row, kg * 16));
            #pragma unroll
            for (int m = 0; m < 4; ++m) {
                acc[m][nf] = MFMA32(ah[m], bh, acc[m][nf]);
                if constexpr (WLO) {
                    if (SWAP) acc[m][nf] = MFMA32(ah[m], blw, acc[m][nf]);
                    else      acc[m][nf] = MFMA32(wlm[m], bh, acc[m][nf]);
                }
            }
        }
        if (!hasNext) break;
        __syncthreads();
        cur ^= 1;
    }

    if (mode == 2) {
        #pragma unroll
        for (int m = 0; m < 4; ++m) {
            #pragma unroll
            for (int nf = 0; nf < 4; ++nf) {
                int col = n0 + wn * 64 + nf * 16 + lr;
                if (col >= NPADo) continue;
                int hh = (o0 + wm * 64 + m * 16) >> 4;
                bool nok = (col < Nn);
                float v[4];
                #pragma unroll
                for (int r = 0; r < 4; ++r) {
                    int row = o0 + wm * 64 + m * 16 + kg * 4 + r;
                    float a = s[row];
                    v[r] = nok ? (acc[m][nf][r] * a + (bias[row] * a + off[row])) * pscale : 0.f;
                }
                unsigned h01 = cvt_pk_bf16(v[0], v[1]);
                unsigned h23 = cvt_pk_bf16(v[2], v[3]);
                float l0 = v[0] - __uint_as_float(h01 << 16);
                float l1 = v[1] - __uint_as_float(h01 & 0xffff0000u);
                float l2 = v[2] - __uint_as_float(h23 << 16);
                float l3 = v[3] - __uint_as_float(h23 & 0xffff0000u);
                uint2 hst = {h01, h23};
                uint2 lst = {cvt_pk_bf16(l0, l1), cvt_pk_bf16(l2, l3)};
                size_t base = ((size_t)(b * 8 + hh) * NPADo + col) * 32 + kg * 4;
                *(uint2*)(out_b + base)      = hst;
                *(uint2*)(out_b + base + 16) = lst;
            }
        }
    } else {
        #pragma unroll
        for (int nf = 0; nf < 4; ++nf) {
            int col_d = o0 + wn * 64 + nf * 16 + lr;
            float a = s[col_d];
            float badd = bias[col_d] * a + off[col_d];
            #pragma unroll
            for (int m = 0; m < 4; ++m) {
                int rown = n0 + wm * 64 + m * 16 + kg * 4;
                float v0 = acc[m][nf][0] * a + badd;
                float v1 = acc[m][nf][1] * a + badd;
                float v2 = acc[m][nf][2] * a + badd;
                float v3 = acc[m][nf][3] * a + badd;
                if (mode == 0) {
                    if (rown < Nn) {
                        float4 vv = {v0, v1, v2, v3};
                        *(float4*)(out_f + ((size_t)b * O + col_d) * Nn + rown) = vv;
                    }
                } else {
                    if (rown + 3 < NPADo) {
                        uint2 st = {cvt_pk_bf16(v0, v1), cvt_pk_bf16(v2, v3)};
                        *(uint2*)(out_b + ((size_t)b * O + col_d) * NPADo + rown) = st;
                    }
                }
            }
        }
    }
}

// ---------------- bias expand: * log2e; pad keys = -inf (exp -> 0) ----------------
__global__ void biasB_expand_kernel(const float* __restrict__ ab, const int* __restrict__ bidx,
                                    short* __restrict__ biasB, int n_off) {
    int i = blockIdx.x * 256 + threadIdx.x;
    int h = blockIdx.y;
    if (i >= NN2 * KPAD) return;
    int q = i / KPAD, key = i - q * KPAD;
    short v = (short)0xFF80;    // bf16 -inf
    if (key < NN) v = f2bf(ab[h * n_off + bidx[q * NN + key]] * LOG2E);
    biasB[(size_t)h * NN2 * KPAD + i] = v;
}

// ---------------- MFMA attention v16 (unchanged from R29/R30) ----------------
__global__ __launch_bounds__(512, 4)
void attn_mfma16_kernel(const short* __restrict__ QT, const short* __restrict__ KT,
                        const short* __restrict__ V, const short* __restrict__ biasB,
                        short* __restrict__ outT) {
    __shared__ __align__(1024) char LDS[2 * 12288 + 8 * 2048];

    const int t = threadIdx.x;
    const int bid = blockIdx.x;
    const int h = bid & 7;
    const int b = bid >> 3;

    const int lane = t & 63, wid = t >> 6;
    const int lr = lane & 15, kg = lane >> 4;
    const int wq0 = wid * 32;

    bf16x8 qb1[2], qb2[2];
    const short* bb[2];
    #pragma unroll
    for (int qf = 0; qf < 2; ++qf) {
        int qg = wq0 + qf * 16 + lr;
        const short* qrow = QT + ((size_t)(b * 8 + h) * QPAD + qg) * 32;
        qb1[qf] = *(const bf16x8*)(qrow + (kg & 1) * 8);
        qb2[qf] = (bf16x8){0, 0, 0, 0, 0, 0, 0, 0};
        if (kg < 2) qb2[qf] = *(const bf16x8*)(qrow + 16 + kg * 8);
        int qs = (qg < NN2) ? qg : (NN2 - 1);
        bb[qf] = biasB + ((size_t)h * NN2 + qs) * KPAD;
    }

    const short* kbase = KT + (size_t)(b * 8 + h) * KPAD * 32;
    const short* vbase = V + ((size_t)b * DH + h * DD) * KPAD;

    f32x4 acc[2][4];
    #pragma unroll
    for (int qf = 0; qf < 2; ++qf)
        #pragma unroll
        for (int nt = 0; nt < 4; ++nt)
            acc[qf][nt] = (f32x4){0.f, 0.f, 0.f, 0.f};
    float sacc[2] = {0.f, 0.f};
    char* PsW = LDS + 24576 + wid * 2048;
    const int swz = (lr & 7) << 4;

    auto STAGE = [&](int buf, int tile) {
        const int k0 = tile * 64;
        char* base = LDS + buf * 12288;
        #pragma unroll
        for (int ci = 0; ci < 2; ++ci) {
            if (ci == 1 && wid >= 4) continue;
            int chunk = (ci == 0) ? wid : wid + 8;
            if (chunk < 4) {
                int row = chunk * 16 + (lane >> 2);
                int pcol = (lane & 3) ^ ((row >> 1) & 3);
                gload16((const char*)(kbase + (size_t)(k0 + row) * 32) + pcol * 16,
                        base + chunk * 1024);
            } else {
                int vrow = (chunk - 4) * 8 + (lane >> 3);
                int pcol = (lane & 7) ^ (vrow & 7);
                gload16((const char*)(vbase + (size_t)vrow * KPAD + k0) + pcol * 16,
                        base + 4096 + (chunk - 4) * 1024);
            }
        }
    };

    auto COMPUTE = [&](int buf, int tile) {
        const int k0 = tile * 64;
        char* cb = LDS + buf * 12288;

        #pragma unroll
        for (int qf = 0; qf < 2; ++qf) {
            if (wq0 + qf * 16 >= NN2) continue;   // dead-q wave-uniform skip

            short4 b4[4];
            #pragma unroll
            for (int nt = 0; nt < 4; ++nt)
                b4[nt] = *(const short4*)(bb[qf] + k0 + nt * 16 + kg * 4);

            f32x4 sc[4];
            __builtin_amdgcn_s_setprio(1);
            #pragma unroll
            for (int nt = 0; nt < 4; ++nt) {
                int row = nt * 16 + lr;
                bf16x8 ka = *(const bf16x8*)(cb + row * 64 + ((kg ^ ((row >> 1) & 3)) * 16));
                sc[nt] = (f32x4){0.f, 0.f, 0.f, 0.f};
                sc[nt] = MFMA32(ka, qb1[qf], sc[nt]);
                sc[nt] = MFMA32(ka, qb2[qf], sc[nt]);
            }
            __builtin_amdgcn_s_setprio(0);

            #pragma unroll
            for (int nt = 0; nt < 4; ++nt) {
                float pv[4];
                #pragma unroll
                for (int r = 0; r < 4; ++r) {
                    float sv = sc[nt][r] + bf2f(((const short*)&b4[nt])[r]);
                    pv[r] = fexp2(sv);
                    sacc[qf] += pv[r];
                }
                uint2 pk2 = {cvt_pk_bf16(pv[0], pv[1]), cvt_pk_bf16(pv[2], pv[3])};
                *(uint2*)(PsW + lr * 128 + ((nt * 32 + kg * 8) ^ swz)) = pk2;
            }

            #pragma unroll
            for (int ks = 0; ks < 2; ++ks) {
                bf16x8 pa = *(const bf16x8*)(PsW + lr * 128 + ((ks * 64 + kg * 16) ^ swz));
                __builtin_amdgcn_s_setprio(1);
                #pragma unroll
                for (int nt = 0; nt < 4; ++nt) {
                    int row = nt * 16 + lr;
                    int pk_ = ks * 4 + kg;
                    bf16x8 vf = *(const bf16x8*)(cb + 4096 + row * 128 + ((pk_ ^ (row & 7)) * 16));
                    acc[qf][nt] = MFMA32(pa, vf, acc[qf][nt]);
                }
                __builtin_amdgcn_s_setprio(0);
            }
        }
    };

    STAGE(0, 0);
    int cur = 0;
    __syncthreads();
    #pragma unroll 1
    for (int tile = 0; tile < 13; ++tile) {
        if (tile + 1 < 13) STAGE(cur ^ 1, tile + 1);
        COMPUTE(cur, tile);
        __syncthreads();
        cur ^= 1;
    }

    #pragma unroll
    for (int qf = 0; qf < 2; ++qf) {
        float sv = sacc[qf];
        sv += __shfl_xor(sv, 16, 64);
        sv += __shfl_xor(sv, 32, 64);
        #pragma unroll
        for (int r = 0; r < 4; ++r) {
            int qrow_ = wq0 + qf * 16 + kg * 4 + r;
            if (qrow_ >= NN2) continue;
            float inv = 1.f / __shfl(sv, kg * 4 + r, 64);
            short* grow = outT + ((size_t)b * NN2 + qrow_) * DH + h * DD;
            #pragma unroll
            for (int nt = 0; nt < 4; ++nt) {
                int d = nt * 16 + lr;
                grow[d] = f2bf(acc[qf][nt][r] * inv);
            }
        }
    }
}

// ---------------- vlgelu: FUSED bn(dwconv) + attnT add + gelu -> gT bf16 ----------------
// Replaces vlocalT + geluE; vlT buffer never materialized (saves ~102MB traffic).
// grid (DH/32, BATCH). Phase A: conv -> LDS tile. Phase B: + attnT, gelu, write gT.
__global__ __launch_bounds__(256)
void vlgelu_kernel(const short* __restrict__ v, const float* __restrict__ vl_w,
                   const float* __restrict__ vl_b, const float* __restrict__ vl_s,
                   const float* __restrict__ vl_o, const short* __restrict__ aT,
                   short* __restrict__ gT) {
    __shared__ float tile[32][201];
    const int cg = blockIdx.x, b = blockIdx.y;
    const int t = threadIdx.x;
    // phase A: bn(dwconv3x3 s2) for 32 channels into LDS [c][n2]
    {
        const int c_l = t >> 3, nsub = t & 7;
        const int c = cg * 32 + c_l;
        const size_t base = ((size_t)b * DH + c) * KPAD;
        const float* w = vl_w + c * 9;
        const float w0 = w[0], w1 = w[1], w2 = w[2], w3 = w[3], w4 = w[4],
                    w5 = w[5], w6 = w[6], w7 = w[7], w8 = w[8];
        const float bias = vl_b[c], sc = vl_s[c], of = vl_o[c];
        for (int n2 = nsub; n2 < NN2; n2 += 8) {
            int i = n2 / RES2, j = n2 % RES2;
            int r0 = 2 * i - 1, c0 = 2 * j - 1;
            float acc = bias;
            if (r0 >= 0) {
                if (c0 >= 0)       acc += bf2f(v[base + r0 * RES + c0])     * w0;
                                   acc += bf2f(v[base + r0 * RES + c0 + 1]) * w1;
                if (c0 + 2 < RES)  acc += bf2f(v[base + r0 * RES + c0 + 2]) * w2;
            }
            {
                if (c0 >= 0)       acc += bf2f(v[base + (r0 + 1) * RES + c0])     * w3;
                                   acc += bf2f(v[base + (r0 + 1) * RES + c0 + 1]) * w4;
                if (c0 + 2 < RES)  acc += bf2f(v[base + (r0 + 1) * RES + c0 + 2]) * w5;
            }
            if (r0 + 2 < RES) {
                if (c0 >= 0)       acc += bf2f(v[base + (r0 + 2) * RES + c0])     * w6;
                                   acc += bf2f(v[base + (r0 + 2) * RES + c0 + 1]) * w7;
                if (c0 + 2 < RES)  acc += bf2f(v[base + (r0 + 2) * RES + c0 + 2]) * w8;
            }
            tile[c_l][n2] = acc * sc + of;
        }
    }
    __syncthreads();
    // phase B: read attnT (coalesced 64B/32 lanes), add, gelu, write gT; zero pad rows
    {
        const int c_l = t & 31, ng = t >> 5;
        const short* ab = aT + (size_t)b * NN2 * DH + cg * 32 + c_l;
        short* gb = gT + (size_t)b * QPAD * DH + cg * 32 + c_l;
        for (int n2 = ng; n2 < NN2; n2 += 8) {
            float s_ = bf2f(ab[(size_t)n2 * DH]) + tile[c_l][n2];
            float g = 0.5f * s_ * (1.f + erff(s_ * 0.70710678118654752440f));
            gb[(size_t)n2 * DH] = f2bf(g);
        }
        for (int n2 = NN2 + ng; n2 < QPAD; n2 += 8)
            gb[(size_t)n2 * DH] = 0;
    }
}

extern "C" void kernel_launch(void* const* d_in, const int* in_sizes, int n_in,
                              void* d_out, int out_size, void* d_ws, size_t ws_size,
                              hipStream_t stream) {
    const float* x     = (const float*)d_in[0];
    const float* ql_w  = (const float*)d_in[1];
    const float* ql_b  = (const float*)d_in[2];
    const float* qp_w  = (const float*)d_in[3];
    const float* qp_b  = (const float*)d_in[4];
    const float* qp_s  = (const float*)d_in[5];
    const float* qp_o  = (const float*)d_in[6];
    const float* k_w   = (const float*)d_in[7];
    const float* k_b   = (const float*)d_in[8];
    const float* k_s   = (const float*)d_in[9];
    const float* k_o   = (const float*)d_in[10];
    const float* v_w   = (const float*)d_in[11];
    const float* v_b   = (const float*)d_in[12];
    const float* v_s   = (const float*)d_in[13];
    const float* v_o   = (const float*)d_in[14];
    const float* vl_w  = (const float*)d_in[15];
    const float* vl_b  = (const float*)d_in[16];
    const float* vl_s  = (const float*)d_in[17];
    const float* vl_o  = (const float*)d_in[18];
    const float* p_w   = (const float*)d_in[19];
    const float* p_b   = (const float*)d_in[20];
    const float* p_s   = (const float*)d_in[21];
    const float* p_o   = (const float*)d_in[22];
    const float* ab    = (const float*)d_in[23];
    const int*   bidx  = (const int*)d_in[24];
    float* out = (float*)d_out;
    int n_off = in_sizes[23] / HEADS;

    char* ws = (char*)d_ws;
    short* qinT_h = (short*)(ws + O_QINT_HI);
    short* xT_h   = (short*)(ws + O_XT_HI);
    short* QT     = (short*)(ws + O_QT);
    short* KT     = (short*)(ws + O_KT);
    short* Vb     = (short*)(ws + O_V);
    short* biasB  = (short*)(ws + O_BIASB);
    short* w_h    = (short*)(ws + O_W_HI);
    short* w_l    = (short*)(ws + O_W_LO);
    short* attnT  = (short*)(ws + O_ATTNT);
    short* gT_h   = (short*)(ws + O_GT_HI);

    // 1. xprep (16 channels/block)
    xprep_kernel<<<dim3(DIMC / 16, BATCH), 256, 0, stream>>>(x, ql_w, ql_b, xT_h, qinT_h);
    // 2. weight splits
    wsplit_kernel<<<dim3(1920), 256, 0, stream>>>(qp_w, k_w, v_w, p_w, w_h, w_l);
    // 3. q projection -> QT packed (pre-scaled by SCALE*log2e)
    gemm_split_kernel<false, false><<<dim3(128), 256, 0, stream>>>(
        w_h + 0, nullptr, qinT_h, qp_b, qp_s, qp_o,
        nullptr, QT, 2, DIMC, NN2, QPAD, QPAD, SCALE * LOG2E, 2, 1, 128);
    // 4. k projection -> KT packed
    gemm_split_kernel<false, false><<<dim3(448), 256, 0, stream>>>(
        w_h + 49152, nullptr, xT_h, k_b, k_s, k_o,
        nullptr, KT, 2, DIMC, NN, XPAD, KPAD, 1.0f, 7, 1, 128);
    // 5. v projection -> bf16, SWAPPED
    gemm_split_kernel<false, true><<<dim3(1792), 256, 0, stream>>>(
        w_h + 98304, nullptr, xT_h, v_b, v_s, v_o,
        nullptr, Vb, 1, DIMC, NN, XPAD, KPAD, 1.0f, 7, 4, 512);
    // 6. bias expand (log2e; pad keys -inf)
    biasB_expand_kernel<<<dim3((NN2 * KPAD + 255) / 256, HEADS), 256, 0, stream>>>(ab, bidx, biasB, n_off);
    // 7. attention -> attnT bf16 (v16)
    attn_mfma16_kernel<<<dim3(HEADS * BATCH), 512, 0, stream>>>(QT, KT, Vb, biasB, attnT);
    // 8. FUSED vlocal + gelu -> gT bf16 (vlT buffer eliminated; pad rows zeroed)
    vlgelu_kernel<<<dim3(DH / 32, BATCH), 256, 0, stream>>>(Vb, vl_w, vl_b, vl_s, vl_o, attnT, gT_h);
    // 9. output projection, SWAPPED, single-term weights
    gemm_split_kernel<false, true><<<dim3(384), 256, 0, stream>>>(
        w_h + 294912, nullptr, gT_h, p_b, p_s, p_o,
        out, nullptr, 0, DH, NN2, QPAD, 0, 1.0f, 2, 3, 384);
}